// Round 1
// baseline (1317.723 us; speedup 1.0000x reference)
//
#include <hip/hip_runtime.h>
#include <math.h>

#define HW_ (256*256)
#define CH 32
#define CH2 64
#define BATCH 4

// ---------------- FFT core: 16 lines of 256-point radix-2 DIT in LDS ----------------
// A layout: line l element i at A[l*257 + i]. tw[j] = exp(sign*2*pi*i*j/256), j<128.
__device__ __forceinline__ void build_tw(float2* tw, float sign) {
    int tid = threadIdx.x;
    if (tid < 128) {
        float ang = sign * 6.2831853071795864769f * (float)tid / 256.0f;
        float s, c; sincosf(ang, &s, &c);
        tw[tid] = make_float2(c, s);
    }
}

__device__ __forceinline__ void fft_core(float2* A, const float2* tw) {
    const int tid = threadIdx.x;
    // bit-reverse permutation (input loaded in natural order)
    for (int idx = tid; idx < 16*256; idx += 256) {
        int l = idx >> 8, i = idx & 255;
        int j = __brev(i) >> 24;
        if (i < j) {
            int base = l*257;
            float2 t = A[base+i]; A[base+i] = A[base+j]; A[base+j] = t;
        }
    }
    __syncthreads();
    for (int s = 1; s <= 8; ++s) {
        int half = 1 << (s-1);
        int shift = 8 - s;
        for (int idx = tid; idx < 16*128; idx += 256) {
            int l = idx >> 7, bf = idx & 127;
            int k = bf & (half-1);
            int g = bf >> (s-1);
            int i0 = l*257 + (g << s) + k;
            int i1 = i0 + half;
            float2 w = tw[k << shift];
            float2 u = A[i0], v = A[i1];
            float tx = v.x*w.x - v.y*w.y;
            float ty = v.x*w.y + v.y*w.x;
            A[i0] = make_float2(u.x + tx, u.y + ty);
            A[i1] = make_float2(u.x - tx, u.y - ty);
        }
        __syncthreads();
    }
}

// ---------------- forward FFT pass 1: rows (real input), yd -> CA ----------------
__global__ __launch_bounds__(256) void k_fft_fwd1(const float* __restrict__ yd, float2* __restrict__ CA) {
    __shared__ float2 A[16*257];
    __shared__ float2 tw[128];
    build_tw(tw, -1.0f);
    int blk = blockIdx.x;
    int bc = blk >> 4, h0 = (blk & 15) << 4;
    const float sc = 1.0f/16.0f;
    const float* src = yd + (size_t)bc*HW_ + (size_t)h0*256;
    for (int idx = threadIdx.x; idx < 16*256; idx += 256) {
        int l = idx >> 8, w = idx & 255;
        A[l*257 + w] = make_float2(src[l*256 + w]*sc, 0.0f);
    }
    __syncthreads();
    fft_core(A, tw);
    float2* dst = CA + (size_t)bc*HW_ + (size_t)h0*256;
    for (int idx = threadIdx.x; idx < 16*256; idx += 256) {
        int l = idx >> 8, w = idx & 255;
        dst[l*256 + w] = A[l*257 + w];
    }
}

// ------- forward FFT pass 2: columns, + fftshift over ALL dims, write concat(re,im) -------
__global__ __launch_bounds__(256) void k_fft_fwd2(const float2* __restrict__ CA, float* __restrict__ FSH) {
    __shared__ float2 A[16*257];
    __shared__ float2 tw[128];
    build_tw(tw, -1.0f);
    int blk = blockIdx.x;
    int bc = blk >> 4, w0 = (blk & 15) << 4;
    int b = bc >> 5, c = bc & 31;
    const float sc = 1.0f/16.0f;
    const float2* src = CA + (size_t)bc*HW_ + w0;
    for (int idx = threadIdx.x; idx < 16*256; idx += 256) {
        int h = idx >> 4, l = idx & 15;
        float2 v = src[(size_t)h*256 + l];
        A[l*257 + h] = make_float2(v.x*sc, v.y*sc);
    }
    __syncthreads();
    fft_core(A, tw);
    // fftshift: out[bt,ct,ht,wt] = F[b,c,h,w] with bt=(b+2)%4, ct=(c+16)%32, ht=(h+128)%256, wt=(w+128)%256
    int bt = (b + 2) & 3;
    int ct = (c + 16) & 31;
    float* dre = FSH + ((size_t)(bt*CH2 + ct))*HW_;
    float* dim = FSH + ((size_t)(bt*CH2 + ct + 32))*HW_;
    for (int idx = threadIdx.x; idx < 16*256; idx += 256) {
        int h = idx >> 4, l = idx & 15;
        int ht = (h + 128) & 255;
        int wt = (w0 + l + 128) & 255;
        float2 v = A[l*257 + h];
        dre[(size_t)ht*256 + wt] = v.x;
        dim[(size_t)ht*256 + wt] = v.y;
    }
}

// ------- inverse FFT pass 1: columns, gathering ifftshift'ed complex from G -------
// Z[b,c,h,w] = complex(G[(b+2)%4, c+32, (h+128)%256, (w+128)%256], G[(b+2)%4, c, ...])
__global__ __launch_bounds__(256) void k_fft_inv1(const float* __restrict__ G, float2* __restrict__ Z1T) {
    __shared__ float2 A[16*257];
    __shared__ float2 tw[128];
    build_tw(tw, 1.0f);
    int blk = blockIdx.x;
    int bc = blk >> 4, w0 = (blk & 15) << 4;
    int b = bc >> 5, c = bc & 31;
    int bs = (b + 2) & 3;
    const float sc = 1.0f/16.0f;
    const float* gre = G + ((size_t)(bs*CH2 + c + 32))*HW_;
    const float* gim = G + ((size_t)(bs*CH2 + c))*HW_;
    for (int idx = threadIdx.x; idx < 16*256; idx += 256) {
        int h = idx >> 4, l = idx & 15;
        int hs = (h + 128) & 255;
        int ws = (w0 + l + 128) & 255;
        A[l*257 + h] = make_float2(gre[(size_t)hs*256 + ws]*sc, gim[(size_t)hs*256 + ws]*sc);
    }
    __syncthreads();
    fft_core(A, tw);
    float2* dst = Z1T + (size_t)bc*HW_;   // [w][h] layout per image
    for (int idx = threadIdx.x; idx < 16*256; idx += 256) {
        int l = idx >> 8, h = idx & 255;
        dst[(size_t)(w0 + l)*256 + h] = A[l*257 + h];
    }
}

// ------- inverse FFT pass 2: rows (over w), abs, WRITE to out -------
__global__ __launch_bounds__(256) void k_fft_inv2(const float2* __restrict__ Z1T, float* __restrict__ out) {
    __shared__ float2 A[16*257];
    __shared__ float2 tw[128];
    build_tw(tw, 1.0f);
    int blk = blockIdx.x;
    int bc = blk >> 4, h0 = (blk & 15) << 4;
    const float sc = 1.0f/16.0f;
    const float2* src = Z1T + (size_t)bc*HW_ + h0;
    for (int idx = threadIdx.x; idx < 16*256; idx += 256) {
        int w = idx >> 4, l = idx & 15;
        float2 v = src[(size_t)w*256 + l];
        A[l*257 + w] = make_float2(v.x*sc, v.y*sc);
    }
    __syncthreads();
    fft_core(A, tw);
    float* dst = out + (size_t)bc*HW_ + (size_t)h0*256;
    for (int idx = threadIdx.x; idx < 16*256; idx += 256) {
        int l = idx >> 8, w = idx & 255;
        float2 v = A[l*257 + w];
        dst[l*256 + w] = sqrtf(v.x*v.x + v.y*v.y);
    }
}

// ---------------- conv1x1: out[b,o,h,w] = sum_c w[o,c] in[b,c,h,w] + bias[o] ----------------
__global__ __launch_bounds__(256) void k_conv1x1(const float* __restrict__ in, const float* __restrict__ w,
                                                 const float* __restrict__ bias, float* __restrict__ out) {
    __shared__ float ts[32*257];
    int blk = blockIdx.x; int b = blk >> 8, h = blk & 255;
    int tid = threadIdx.x;
    const float* src = in + (size_t)b*CH*HW_ + (size_t)h*256;
    for (int idx = tid; idx < 32*256; idx += 256) {
        int c = idx >> 8, ww = idx & 255;
        ts[c*257 + ww] = src[(size_t)c*HW_ + ww];
    }
    __syncthreads();
    float acc[32];
    #pragma unroll
    for (int o = 0; o < 32; ++o) acc[o] = bias[o];
    for (int c = 0; c < 32; ++c) {
        float v = ts[c*257 + tid];
        #pragma unroll
        for (int o = 0; o < 32; ++o) acc[o] += w[o*32 + c] * v;
    }
    float* dst = out + (size_t)b*CH*HW_ + (size_t)h*256 + tid;
    #pragma unroll
    for (int o = 0; o < 32; ++o) dst[(size_t)o*HW_] = acc[o];
}

// ---------------- conv3x3 SAME, 64ch -> 64ch, optional relu on input ----------------
__global__ __launch_bounds__(256) void k_conv3x3(const float* __restrict__ in, const float* __restrict__ wgt,
                                                  const float* __restrict__ bias, float* __restrict__ out,
                                                  int relu_in) {
    __shared__ float tile[3*264];
    int blk = blockIdx.x; int b = blk >> 8, h = blk & 255;
    int tid = threadIdx.x;
    int lane = tid & 63;
    int ocg = __builtin_amdgcn_readfirstlane(tid >> 6); // wave-uniform 0..3
    float acc[16][4];
    #pragma unroll
    for (int j = 0; j < 16; ++j) {
        float bv = bias[ocg*16 + j];
        acc[j][0]=bv; acc[j][1]=bv; acc[j][2]=bv; acc[j][3]=bv;
    }
    const float* inb = in + (size_t)b*CH2*HW_;
    for (int ic = 0; ic < 64; ++ic) {
        __syncthreads();
        for (int idx = tid; idx < 3*258; idx += 256) {
            int r = idx / 258;
            int k = idx - r*258;
            int hh = h - 1 + r;
            int wcol = k - 1;
            float v = 0.0f;
            if (hh >= 0 && hh < 256 && wcol >= 0 && wcol < 256) {
                v = inb[(size_t)ic*HW_ + (size_t)hh*256 + wcol];
                if (relu_in) v = fmaxf(v, 0.0f);
            }
            tile[r*264 + k] = v;
        }
        __syncthreads();
        float vv[4][9];
        #pragma unroll
        for (int p = 0; p < 4; ++p) {
            int wb = lane + p*64;
            #pragma unroll
            for (int r = 0; r < 3; ++r) {
                vv[p][r*3+0] = tile[r*264 + wb];
                vv[p][r*3+1] = tile[r*264 + wb+1];
                vv[p][r*3+2] = tile[r*264 + wb+2];
            }
        }
        const float* wp = wgt + ((size_t)(ocg*16)*64 + ic)*9;
        #pragma unroll
        for (int j = 0; j < 16; ++j) {
            float w0 = wp[j*576+0], w1 = wp[j*576+1], w2 = wp[j*576+2];
            float w3 = wp[j*576+3], w4 = wp[j*576+4], w5 = wp[j*576+5];
            float w6 = wp[j*576+6], w7 = wp[j*576+7], w8 = wp[j*576+8];
            #pragma unroll
            for (int p = 0; p < 4; ++p) {
                acc[j][p] += w0*vv[p][0] + w1*vv[p][1] + w2*vv[p][2]
                           + w3*vv[p][3] + w4*vv[p][4] + w5*vv[p][5]
                           + w6*vv[p][6] + w7*vv[p][7] + w8*vv[p][8];
            }
        }
    }
    float* outb = out + (size_t)b*CH2*HW_ + (size_t)h*256;
    #pragma unroll
    for (int j = 0; j < 16; ++j) {
        int oc = ocg*16 + j;
        #pragma unroll
        for (int p = 0; p < 4; ++p)
            outb[(size_t)oc*HW_ + lane + p*64] = acc[j][p];
    }
}

// ---------------- Gram: M[b,a,e] = sum_n x[b,a,n]*dk[b,e,n]; row sums for bias terms ----------------
__global__ __launch_bounds__(256) void k_gram(const float* __restrict__ x, const float* __restrict__ dft,
                                               float* __restrict__ M, float* __restrict__ Sx, float* __restrict__ Sdk) {
    __shared__ __align__(16) float xs[32*132];
    __shared__ __align__(16) float ds[32*132];
    int blk = blockIdx.x; int b = blk >> 8, h = blk & 255;
    int tid = threadIdx.x;
    int a = tid >> 3, e0 = (tid & 7) << 2;
    float macc[4] = {0,0,0,0};
    float srow = 0.0f;
    const float* xb = x + (size_t)b*CH*HW_ + (size_t)h*256;
    const float* db = dft + (size_t)b*CH2*HW_ + (size_t)h*256;
    for (int half = 0; half < 2; ++half) {
        for (int idx = tid; idx < 32*128; idx += 256) {
            int cc = idx >> 7, w = idx & 127;
            xs[cc*132 + w] = xb[(size_t)cc*HW_ + half*128 + w];
            ds[cc*132 + w] = db[(size_t)cc*HW_ + half*128 + w];
        }
        __syncthreads();
        for (int w4 = 0; w4 < 32; ++w4) {
            float4 xv = *(const float4*)&xs[a*132 + w4*4];
            #pragma unroll
            for (int j = 0; j < 4; ++j) {
                float4 dv = *(const float4*)&ds[(e0+j)*132 + w4*4];
                macc[j] += xv.x*dv.x + xv.y*dv.y + xv.z*dv.z + xv.w*dv.w;
            }
        }
        if (tid < 32) { float s=0; for (int w=0;w<128;++w) s += xs[tid*132+w]; srow += s; }
        else if (tid < 64) { float s=0; for (int w=0;w<128;++w) s += ds[(tid-32)*132+w]; srow += s; }
        __syncthreads();
    }
    #pragma unroll
    for (int j = 0; j < 4; ++j) atomicAdd(&M[(b*32 + a)*32 + e0 + j], macc[j]);
    if (tid < 32) atomicAdd(&Sx[b*32 + tid], srow);
    else if (tid < 64) atomicAdd(&Sdk[b*32 + tid - 32], srow);
}

// ---------------- tiny attention: att = Wq M Wk^T (+bias), softmax over c, att2 = att Wv ----------------
__global__ __launch_bounds__(256) void k_att(const float* __restrict__ M, const float* __restrict__ Sx,
                                              const float* __restrict__ Sdk,
                                              const float* __restrict__ wq, const float* __restrict__ bq,
                                              const float* __restrict__ wk, const float* __restrict__ bk,
                                              const float* __restrict__ wv, const float* __restrict__ bv,
                                              float* __restrict__ att2, float* __restrict__ sout) {
    __shared__ float Mls[1024], T1[1024], attls[32*33];
    __shared__ float wqs[1024], wks[1024], wvs[1024];
    __shared__ float q1[32], k1[32];
    int tid = threadIdx.x;
    for (int idx = tid; idx < 1024; idx += 256) { wqs[idx] = wq[idx]; wks[idx] = wk[idx]; wvs[idx] = wv[idx]; }
    __syncthreads();
    for (int b = 0; b < 4; ++b) {
        for (int idx = tid; idx < 1024; idx += 256) Mls[idx] = M[b*1024 + idx];
        __syncthreads();
        if (tid < 32) { float s=0; for (int a=0;a<32;++a) s += wqs[tid*32+a]*Sx[b*32+a]; q1[tid]=s; }
        else if (tid < 64) { int d=tid-32; float s=0; for (int e=0;e<32;++e) s += wks[d*32+e]*Sdk[b*32+e]; k1[d]=s; }
        for (int idx = tid; idx < 1024; idx += 256) {
            int c = idx >> 5, e = idx & 31;
            float s = 0;
            for (int a=0;a<32;++a) s += wqs[c*32+a]*Mls[a*32+e];
            T1[idx] = s;
        }
        __syncthreads();
        for (int idx = tid; idx < 1024; idx += 256) {
            int c = idx >> 5, d = idx & 31;
            float s = 0;
            for (int e=0;e<32;++e) s += T1[c*32+e]*wks[d*32+e];
            s += bq[c]*k1[d] + bk[d]*q1[c] + 65536.0f*bq[c]*bk[d];
            attls[c*33+d] = s;
        }
        __syncthreads();
        if (tid < 32) {  // softmax over c for column d=tid
            int d = tid;
            float mx = -1e30f;
            for (int c=0;c<32;++c) mx = fmaxf(mx, attls[c*33+d]);
            float sum = 0;
            for (int c=0;c<32;++c) { float e_ = expf(attls[c*33+d]-mx); attls[c*33+d]=e_; sum+=e_; }
            float inv = 1.0f/sum;
            for (int c=0;c<32;++c) attls[c*33+d] *= inv;
        }
        __syncthreads();
        for (int idx = tid; idx < 1024; idx += 256) {
            int c = idx >> 5, e = idx & 31;
            float s = 0;
            for (int d=0; d<32; ++d) s += attls[c*33+d]*wvs[d*32+e];
            att2[b*1024 + idx] = s;
        }
        if (tid < 32) {
            float s=0; for (int d=0;d<32;++d) s += attls[tid*33+d]*bv[d];
            sout[b*32+tid] = s;
        }
        __syncthreads();
    }
}

// ---------------- final: out += att2 @ dv + s ----------------
__global__ __launch_bounds__(256) void k_out(const float* __restrict__ dft, const float* __restrict__ att2,
                                              const float* __restrict__ sv, float* __restrict__ out) {
    __shared__ float dvs[32*257];
    int blk = blockIdx.x; int b = blk >> 8, h = blk & 255;
    int tid = threadIdx.x;
    const float* db = dft + ((size_t)b*CH2 + 32)*HW_ + (size_t)h*256;
    for (int idx = tid; idx < 32*256; idx += 256) {
        int e = idx >> 8, w = idx & 255;
        dvs[e*257 + w] = db[(size_t)e*HW_ + w];
    }
    __syncthreads();
    const float* A2 = att2 + b*1024;
    float acc[32];
    #pragma unroll
    for (int c = 0; c < 32; ++c) acc[c] = sv[b*32 + c];
    for (int e = 0; e < 32; ++e) {
        float dval = dvs[e*257 + tid];
        #pragma unroll
        for (int c = 0; c < 32; ++c) acc[c] += A2[c*32 + e] * dval;
    }
    float* ob = out + (size_t)b*CH*HW_ + (size_t)h*256 + tid;
    #pragma unroll
    for (int c = 0; c < 32; ++c) ob[(size_t)c*HW_] += acc[c];
}

extern "C" void kernel_launch(void* const* d_in, const int* in_sizes, int n_in,
                              void* d_out, int out_size, void* d_ws, size_t ws_size,
                              hipStream_t stream) {
    const float* x  = (const float*)d_in[0];
    const float* y  = (const float*)d_in[1];
    const float* wq = (const float*)d_in[2];
    const float* bq = (const float*)d_in[3];
    const float* wk = (const float*)d_in[4];
    const float* bk = (const float*)d_in[5];
    const float* wv = (const float*)d_in[6];
    const float* bv = (const float*)d_in[7];
    const float* wd = (const float*)d_in[8];
    const float* bd = (const float*)d_in[9];
    const float* wc = (const float*)d_in[10];
    const float* bc = (const float*)d_in[11];
    const float* wi = (const float*)d_in[12];
    const float* bi = (const float*)d_in[13];
    float* out = (float*)d_out;

    char* ws = (char*)d_ws;
    size_t o = 0;
    float*  R1  = (float*)(ws + o);  o += (size_t)BATCH*CH*HW_*4;    // yd            (33.5 MB)
    float2* CA  = (float2*)(ws + o); o += (size_t)BATCH*CH*HW_*8;    // complex / G   (67 MB)
    float*  FSH = (float*)(ws + o);  o += (size_t)BATCH*CH2*HW_*4;   // fsh / Z1T     (67 MB)
    float*  DFT = (float*)(ws + o);  o += (size_t)BATCH*CH2*HW_*4;   // dft           (67 MB)
    float*  Mb  = (float*)(ws + o);  o += 4096*4;
    float*  Sxb = (float*)(ws + o);  o += 128*4;
    float*  Sdb = (float*)(ws + o);  o += 128*4;
    float*  A2b = (float*)(ws + o);  o += 4096*4;
    float*  Svb = (float*)(ws + o);  o += 128*4;
    if (ws_size < o) return;  // workspace too small: fail loudly via wrong output

    float*  Gb  = (float*)CA;    // alias: CA free after fwd2
    float2* Z1T = (float2*)FSH;  // alias: FSH free after first conv3x3

    hipMemsetAsync(Mb, 0, (4096 + 128 + 128) * 4, stream);

    k_conv1x1<<<1024, 256, 0, stream>>>(y, wd, bd, R1);
    k_fft_fwd1<<<2048, 256, 0, stream>>>(R1, CA);
    k_fft_fwd2<<<2048, 256, 0, stream>>>(CA, FSH);
    k_conv3x3<<<1024, 256, 0, stream>>>(FSH, wc, bc, DFT, 0);
    k_conv3x3<<<1024, 256, 0, stream>>>(DFT, wi, bi, Gb, 1);
    k_gram<<<1024, 256, 0, stream>>>(x, DFT, Mb, Sxb, Sdb);
    k_att<<<1, 256, 0, stream>>>(Mb, Sxb, Sdb, wq, bq, wk, bk, wv, bv, A2b, Svb);
    k_fft_inv1<<<2048, 256, 0, stream>>>(Gb, Z1T);
    k_fft_inv2<<<2048, 256, 0, stream>>>(Z1T, out);
    k_out<<<1024, 256, 0, stream>>>(DFT, A2b, Svb, out);
}

// Round 2
// 486.152 us; speedup vs baseline: 2.7105x; 2.7105x over previous
//
#include <hip/hip_runtime.h>
#include <math.h>

#define HW_ (256*256)
#define CH 32
#define CH2 64
#define BATCH 4

typedef short bf16x8 __attribute__((ext_vector_type(8)));
typedef float f32x4 __attribute__((ext_vector_type(4)));

__device__ __forceinline__ unsigned short f2bf(float f) {
    union { float f; unsigned u; } v; v.f = f;
    unsigned r = v.u + 0x7fffu + ((v.u >> 16) & 1u);
    return (unsigned short)(r >> 16);
}
__device__ __forceinline__ float bf2f(unsigned h) {
    union { unsigned u; float f; } v; v.u = h << 16;
    return v.f;
}

// slot -> true channel index for FSH channel-last layout (see k_fft_fwd2)
__device__ __forceinline__ int ctof_slot(int s) {
    return s < 16 ? s + 16 : s < 32 ? s + 32 : s < 48 ? s - 32 : s - 16;
}

// ---------------- FFT core: 16 lines of 256-point radix-2 DIT in LDS ----------------
__device__ __forceinline__ void build_tw(float2* tw, float sign) {
    int tid = threadIdx.x;
    if (tid < 128) {
        float ang = sign * 6.2831853071795864769f * (float)tid / 256.0f;
        float s, c; sincosf(ang, &s, &c);
        tw[tid] = make_float2(c, s);
    }
}

__device__ __forceinline__ void fft_core(float2* A, const float2* tw) {
    const int tid = threadIdx.x;
    for (int idx = tid; idx < 16*256; idx += 256) {
        int l = idx >> 8, i = idx & 255;
        int j = __brev(i) >> 24;
        if (i < j) {
            int base = l*257;
            float2 t = A[base+i]; A[base+i] = A[base+j]; A[base+j] = t;
        }
    }
    __syncthreads();
    for (int s = 1; s <= 8; ++s) {
        int half = 1 << (s-1);
        int shift = 8 - s;
        for (int idx = tid; idx < 16*128; idx += 256) {
            int l = idx >> 7, bf = idx & 127;
            int k = bf & (half-1);
            int g = bf >> (s-1);
            int i0 = l*257 + (g << s) + k;
            int i1 = i0 + half;
            float2 w = tw[k << shift];
            float2 u = A[i0], v = A[i1];
            float tx = v.x*w.x - v.y*w.y;
            float ty = v.x*w.y + v.y*w.x;
            A[i0] = make_float2(u.x + tx, u.y + ty);
            A[i1] = make_float2(u.x - tx, u.y - ty);
        }
        __syncthreads();
    }
}

// ---------------- fwd FFT pass 1: rows; write TRANSPOSED CAt[bc][w][h] ----------------
__global__ __launch_bounds__(256) void k_fft_fwd1(const float* __restrict__ yd, float2* __restrict__ CAt) {
    __shared__ float2 A[16*257];
    __shared__ float2 tw[128];
    build_tw(tw, -1.0f);
    int blk = blockIdx.x;
    int bc = blk >> 4, h0 = (blk & 15) << 4;
    const float sc = 1.0f/16.0f;
    const float* src = yd + (size_t)bc*HW_ + (size_t)h0*256;
    for (int idx = threadIdx.x; idx < 16*256; idx += 256) {
        int l = idx >> 8, w = idx & 255;
        A[l*257 + w] = make_float2(src[l*256 + w]*sc, 0.0f);
    }
    __syncthreads();
    fft_core(A, tw);
    int t = threadIdx.x;           // t = freq index w
    float2* dst = CAt + (size_t)bc*HW_ + (size_t)t*256 + h0;
    #pragma unroll
    for (int l = 0; l < 16; ++l) dst[l] = A[l*257 + t];   // 128B contiguous per lane
}

// -------- fwd FFT pass 2: block=(b,chalf,w): 16 channels' h-columns; FFT over h;
//          write channel-last bf16 FSH[bt][ht][wt][slot] with fftshift folded in --------
// slot layout per px-row: [0..15]=re(c16..31) [16..31]=im(c16..31)->ct48..63
//                         [32..47]=re(c0..15)->ct0..15 [48..63]=im -> ct32..47
__global__ __launch_bounds__(256) void k_fft_fwd2(const float2* __restrict__ CAt, unsigned short* __restrict__ FSH) {
    __shared__ float2 A[16*257];
    __shared__ float2 tw[128];
    build_tw(tw, -1.0f);
    int blk = blockIdx.x;
    int b = blk >> 9, chalf = (blk >> 8) & 1, w = blk & 255;
    const float sc = 1.0f/16.0f;
    const float2* src = CAt + (((size_t)(b*32 + chalf*16))*256 + w)*256;
    for (int idx = threadIdx.x; idx < 16*256; idx += 256) {
        int l = idx >> 8, h = idx & 255;
        float2 v = src[(size_t)l*HW_ + h];
        A[l*257 + h] = make_float2(v.x*sc, v.y*sc);
    }
    __syncthreads();
    fft_core(A, tw);
    int t = threadIdx.x;           // t = freq index h
    int bt = (b + 2) & 3;
    int ht = (t + 128) & 255;
    int wt = (w + 128) & 255;
    unsigned short pk[32];
    #pragma unroll
    for (int l = 0; l < 16; ++l) {
        float2 v = A[l*257 + t];
        pk[l]      = f2bf(v.x);
        pk[16 + l] = f2bf(v.y);
    }
    unsigned short* dst = FSH + ((((size_t)bt*256 + ht)*256 + wt)*64 + chalf*32);
    uint4* d4 = (uint4*)dst;
    const uint4* s4 = (const uint4*)pk;
    d4[0] = s4[0]; d4[1] = s4[1]; d4[2] = s4[2]; d4[3] = s4[3];
}

// ---------------- weight pre-pack: wpk[tap][oc][ic(slot)] bf16 ----------------
__global__ __launch_bounds__(256) void k_wpack(const float* __restrict__ src, unsigned short* __restrict__ dst, int perm) {
    int i = blockIdx.x*256 + threadIdx.x;
    if (i >= 9*64*64) return;
    int tap = i >> 12, rem = i & 4095, oc = rem >> 6, s = rem & 63;
    int ic = perm ? ctof_slot(s) : s;
    dst[i] = f2bf(src[((size_t)(oc*64 + ic))*9 + tap]);
}

// ---------------- conv3x3 via MFMA implicit GEMM ----------------
// in_cl: channel-last bf16 [b][h][w][64] (MODE==1 applies relu on load)
// wpk:   [9][64][64] bf16 (ic order matches in_cl channel order)
// MODE 0: out = channel-last bf16 [b][h][w][64]   (D[m=oc][n=px])
// MODE 1: out = planar bf16 [b][oc][h][w]         (D[m=px][n=oc])
template<int MODE>
__global__ __launch_bounds__(256) void k_conv3(const unsigned short* __restrict__ in_cl,
                                               const unsigned short* __restrict__ wpk,
                                               const float* __restrict__ bias,
                                               unsigned short* __restrict__ outp) {
    __shared__ __align__(16) char XsRaw[3*1040*16];   // [3 rows][130 cols][64 ic] bf16, swizzled
    __shared__ __align__(16) char WsRaw[8192];        // [64 oc][64 ic] bf16, swizzled
    int tid = threadIdx.x;
    int blk = blockIdx.x;
    int wseg = blk & 1, h = (blk >> 1) & 255, b = blk >> 9;
    int w0 = wseg * 128;

    // ---- stage X tile ----
    for (int r = 0; r < 3; ++r) {
        int hh = h - 1 + r;
        bool hv = (hh >= 0) && (hh < 256);
        const unsigned short* rowp = in_cl + (((size_t)b*256 + hh)*256)*64;
        for (int gl = tid; gl < 1040; gl += 256) {
            int col = gl >> 3, hseg = gl & 7;
            int wcol = w0 - 1 + col;
            uint4 v = make_uint4(0,0,0,0);
            if (hv && wcol >= 0 && wcol < 256) {
                v = *(const uint4*)(rowp + (size_t)wcol*64 + hseg*8);
                if (MODE == 1) {   // relu on bf16 bits
                    unsigned* pv = (unsigned*)&v;
                    #pragma unroll
                    for (int q = 0; q < 4; ++q) {
                        unsigned a = pv[q];
                        unsigned lo = a & 0xffffu, hi = a >> 16;
                        if (lo & 0x8000u) lo = 0;
                        if (hi & 0x8000u) hi = 0;
                        pv[q] = lo | (hi << 16);
                    }
                }
            }
            int byte = ((r*1040 + gl) << 4) ^ ((col & 7) << 4);
            *(uint4*)(XsRaw + byte) = v;
        }
    }

    int lane = tid & 63;
    int wv = tid >> 6;
    int l16 = lane & 15, lq = lane >> 4;
    int pxbase = wv * 32;

    f32x4 acc[4][2];
    #pragma unroll
    for (int i = 0; i < 4; ++i)
        #pragma unroll
        for (int j = 0; j < 2; ++j) acc[i][j] = (f32x4)0.0f;

    for (int tap = 0; tap < 9; ++tap) {
        __syncthreads();
        {   // stage W for this tap: 512 granules of 16B
            const uint4* wsrc = (const uint4*)(wpk + (size_t)tap*4096);
            #pragma unroll
            for (int q = 0; q < 2; ++q) {
                int g = tid*2 + q;
                int oc = g >> 3;
                int byte = (g << 4) ^ ((oc & 7) << 4);
                *(uint4*)(WsRaw + byte) = wsrc[g];
            }
        }
        __syncthreads();
        int dy = tap / 3, dx = tap - dy*3;
        #pragma unroll
        for (int kk = 0; kk < 2; ++kk) {
            int hseg = kk*4 + lq;
            bf16x8 xf[2], wf[4];
            #pragma unroll
            for (int j = 0; j < 2; ++j) {
                int col = pxbase + j*16 + l16 + dx;
                int byte = ((dy*1040 + col*8 + hseg) << 4) ^ ((col & 7) << 4);
                xf[j] = *(const bf16x8*)(XsRaw + byte);
            }
            #pragma unroll
            for (int i = 0; i < 4; ++i) {
                int oc = i*16 + l16;
                int byte = ((oc*8 + hseg) << 4) ^ ((oc & 7) << 4);
                wf[i] = *(const bf16x8*)(WsRaw + byte);
                #pragma unroll
                for (int j = 0; j < 2; ++j) {
                    if (MODE == 0)
                        acc[i][j] = __builtin_amdgcn_mfma_f32_16x16x32_bf16(wf[i], xf[j], acc[i][j], 0, 0, 0);
                    else
                        acc[i][j] = __builtin_amdgcn_mfma_f32_16x16x32_bf16(xf[j], wf[i], acc[i][j], 0, 0, 0);
                }
            }
        }
    }

    if (MODE == 0) {
        // D[m=oc = i*16+lq*4+r][n=px = pxbase+j*16+l16] -> channel-last
        #pragma unroll
        for (int j = 0; j < 2; ++j) {
            int px = w0 + pxbase + j*16 + l16;
            unsigned short* orow = outp + (((size_t)b*256 + h)*256 + px)*64;
            #pragma unroll
            for (int i = 0; i < 4; ++i) {
                int oc0 = i*16 + lq*4;
                float4 bv = *(const float4*)(bias + oc0);
                unsigned short c0 = f2bf(acc[i][j][0] + bv.x);
                unsigned short c1 = f2bf(acc[i][j][1] + bv.y);
                unsigned short c2 = f2bf(acc[i][j][2] + bv.z);
                unsigned short c3 = f2bf(acc[i][j][3] + bv.w);
                uint2 u;
                u.x = (unsigned)c0 | ((unsigned)c1 << 16);
                u.y = (unsigned)c2 | ((unsigned)c3 << 16);
                *(uint2*)(orow + oc0) = u;
            }
        }
    } else {
        // D[m=px = pxbase+j*16+lq*4+r][n=oc = i*16+l16] -> planar
        #pragma unroll
        for (int i = 0; i < 4; ++i) {
            int oc = i*16 + l16;
            float bv = bias[oc];
            unsigned short* oplane = outp + ((size_t)b*64 + oc)*HW_ + (size_t)h*256;
            #pragma unroll
            for (int j = 0; j < 2; ++j) {
                int px0 = w0 + pxbase + j*16 + lq*4;
                unsigned short c0 = f2bf(acc[i][j][0] + bv);
                unsigned short c1 = f2bf(acc[i][j][1] + bv);
                unsigned short c2 = f2bf(acc[i][j][2] + bv);
                unsigned short c3 = f2bf(acc[i][j][3] + bv);
                uint2 u;
                u.x = (unsigned)c0 | ((unsigned)c1 << 16);
                u.y = (unsigned)c2 | ((unsigned)c3 << 16);
                *(uint2*)(oplane + px0) = u;
            }
        }
    }
}

// ---------------- conv1x1 (fp32, unchanged) ----------------
__global__ __launch_bounds__(256) void k_conv1x1(const float* __restrict__ in, const float* __restrict__ w,
                                                 const float* __restrict__ bias, float* __restrict__ out) {
    __shared__ float ts[32*257];
    int blk = blockIdx.x; int b = blk >> 8, h = blk & 255;
    int tid = threadIdx.x;
    const float* src = in + (size_t)b*CH*HW_ + (size_t)h*256;
    for (int idx = tid; idx < 32*256; idx += 256) {
        int c = idx >> 8, ww = idx & 255;
        ts[c*257 + ww] = src[(size_t)c*HW_ + ww];
    }
    __syncthreads();
    float acc[32];
    #pragma unroll
    for (int o = 0; o < 32; ++o) acc[o] = bias[o];
    for (int c = 0; c < 32; ++c) {
        float v = ts[c*257 + tid];
        #pragma unroll
        for (int o = 0; o < 32; ++o) acc[o] += w[o*32 + c] * v;
    }
    float* dst = out + (size_t)b*CH*HW_ + (size_t)h*256 + tid;
    #pragma unroll
    for (int o = 0; o < 32; ++o) dst[(size_t)o*HW_] = acc[o];
}

// ---------------- Gram: M[a,e] = sum_n x[a,n]*dk[e,n] (dk = DFT_cl ct 0..31) ----------------
__global__ __launch_bounds__(256) void k_gram(const float* __restrict__ x, const unsigned short* __restrict__ dcl,
                                              float* __restrict__ M, float* __restrict__ Sx, float* __restrict__ Sdk) {
    __shared__ float xs[32*257];
    __shared__ __align__(16) unsigned short ds[256*32];
    int blk = blockIdx.x; int b = blk >> 8, h = blk & 255;
    int tid = threadIdx.x;
    const float* xb = x + (size_t)b*CH*HW_ + (size_t)h*256;
    for (int idx = tid; idx < 8192; idx += 256) {
        int c = idx >> 8, w = idx & 255;
        xs[c*257 + w] = xb[(size_t)c*HW_ + w];
    }
    {
        const uint4* src = (const uint4*)(dcl + (((size_t)b*256 + h)*256)*64);
        uint4* dst = (uint4*)ds;
        for (int g = tid; g < 1024; g += 256) {
            int px = g >> 2, q = g & 3;
            dst[g] = src[px*8 + q];
        }
    }
    __syncthreads();
    int a = tid >> 3, e0 = (tid & 7) << 2;
    float macc[4] = {0,0,0,0};
    for (int px = 0; px < 256; ++px) {
        float xv = xs[a*257 + px];
        uint2 dv = *(const uint2*)(ds + px*32 + e0);
        macc[0] += xv * bf2f(dv.x & 0xffffu);
        macc[1] += xv * bf2f(dv.x >> 16);
        macc[2] += xv * bf2f(dv.y & 0xffffu);
        macc[3] += xv * bf2f(dv.y >> 16);
    }
    #pragma unroll
    for (int j = 0; j < 4; ++j) atomicAdd(&M[((size_t)b*32 + a)*32 + e0 + j], macc[j]);
    if (tid < 32) {
        float s = 0; for (int w = 0; w < 256; ++w) s += xs[tid*257 + w];
        atomicAdd(&Sx[b*32 + tid], s);
    } else if (tid < 64) {
        int e = tid - 32; float s = 0;
        for (int px = 0; px < 256; ++px) s += bf2f(ds[px*32 + e]);
        atomicAdd(&Sdk[b*32 + e], s);
    }
}

// ---------------- tiny attention (unchanged) ----------------
__global__ __launch_bounds__(256) void k_att(const float* __restrict__ M, const float* __restrict__ Sx,
                                              const float* __restrict__ Sdk,
                                              const float* __restrict__ wq, const float* __restrict__ bq,
                                              const float* __restrict__ wk, const float* __restrict__ bk,
                                              const float* __restrict__ wv, const float* __restrict__ bv,
                                              float* __restrict__ att2, float* __restrict__ sout) {
    __shared__ float Mls[1024], T1[1024], attls[32*33];
    __shared__ float wqs[1024], wks[1024], wvs[1024];
    __shared__ float q1[32], k1[32];
    int tid = threadIdx.x;
    for (int idx = tid; idx < 1024; idx += 256) { wqs[idx] = wq[idx]; wks[idx] = wk[idx]; wvs[idx] = wv[idx]; }
    __syncthreads();
    for (int b = 0; b < 4; ++b) {
        for (int idx = tid; idx < 1024; idx += 256) Mls[idx] = M[b*1024 + idx];
        __syncthreads();
        if (tid < 32) { float s=0; for (int a=0;a<32;++a) s += wqs[tid*32+a]*Sx[b*32+a]; q1[tid]=s; }
        else if (tid < 64) { int d=tid-32; float s=0; for (int e=0;e<32;++e) s += wks[d*32+e]*Sdk[b*32+e]; k1[d]=s; }
        for (int idx = tid; idx < 1024; idx += 256) {
            int c = idx >> 5, e = idx & 31;
            float s = 0;
            for (int a=0;a<32;++a) s += wqs[c*32+a]*Mls[a*32+e];
            T1[idx] = s;
        }
        __syncthreads();
        for (int idx = tid; idx < 1024; idx += 256) {
            int c = idx >> 5, d = idx & 31;
            float s = 0;
            for (int e=0;e<32;++e) s += T1[c*32+e]*wks[d*32+e];
            s += bq[c]*k1[d] + bk[d]*q1[c] + 65536.0f*bq[c]*bk[d];
            attls[c*33+d] = s;
        }
        __syncthreads();
        if (tid < 32) {
            int d = tid;
            float mx = -1e30f;
            for (int c=0;c<32;++c) mx = fmaxf(mx, attls[c*33+d]);
            float sum = 0;
            for (int c=0;c<32;++c) { float e_ = expf(attls[c*33+d]-mx); attls[c*33+d]=e_; sum+=e_; }
            float inv = 1.0f/sum;
            for (int c=0;c<32;++c) attls[c*33+d] *= inv;
        }
        __syncthreads();
        for (int idx = tid; idx < 1024; idx += 256) {
            int c = idx >> 5, e = idx & 31;
            float s = 0;
            for (int d=0; d<32; ++d) s += attls[c*33+d]*wvs[d*32+e];
            att2[b*1024 + idx] = s;
        }
        if (tid < 32) {
            float s=0; for (int d=0;d<32;++d) s += attls[tid*33+d]*bv[d];
            sout[b*32+tid] = s;
        }
        __syncthreads();
    }
}

// ---------------- inv FFT pass 1: columns, ifftshift gather from planar bf16 G ----------------
__global__ __launch_bounds__(256) void k_fft_inv1(const unsigned short* __restrict__ G, float2* __restrict__ Z1T) {
    __shared__ float2 A[16*257];
    __shared__ float2 tw[128];
    build_tw(tw, 1.0f);
    int blk = blockIdx.x;
    int bc = blk >> 4, w0 = (blk & 15) << 4;
    int b = bc >> 5, c = bc & 31;
    int bs = (b + 2) & 3;
    const float sc = 1.0f/16.0f;
    const unsigned short* gre = G + ((size_t)(bs*CH2 + c + 32))*HW_;
    const unsigned short* gim = G + ((size_t)(bs*CH2 + c))*HW_;
    for (int idx = threadIdx.x; idx < 16*256; idx += 256) {
        int h = idx >> 4, l = idx & 15;
        int hs = (h + 128) & 255;
        int ws = (w0 + l + 128) & 255;
        A[l*257 + h] = make_float2(bf2f(gre[(size_t)hs*256 + ws])*sc, bf2f(gim[(size_t)hs*256 + ws])*sc);
    }
    __syncthreads();
    fft_core(A, tw);
    float2* dst = Z1T + (size_t)bc*HW_;
    for (int idx = threadIdx.x; idx < 16*256; idx += 256) {
        int l = idx >> 8, h = idx & 255;
        dst[(size_t)(w0 + l)*256 + h] = A[l*257 + h];
    }
}

// ---------------- inv FFT pass 2: rows, abs -> out ----------------
__global__ __launch_bounds__(256) void k_fft_inv2(const float2* __restrict__ Z1T, float* __restrict__ out) {
    __shared__ float2 A[16*257];
    __shared__ float2 tw[128];
    build_tw(tw, 1.0f);
    int blk = blockIdx.x;
    int bc = blk >> 4, h0 = (blk & 15) << 4;
    const float sc = 1.0f/16.0f;
    const float2* src = Z1T + (size_t)bc*HW_ + h0;
    for (int idx = threadIdx.x; idx < 16*256; idx += 256) {
        int w = idx >> 4, l = idx & 15;
        float2 v = src[(size_t)w*256 + l];
        A[l*257 + w] = make_float2(v.x*sc, v.y*sc);
    }
    __syncthreads();
    fft_core(A, tw);
    float* dst = out + (size_t)bc*HW_ + (size_t)h0*256;
    for (int idx = threadIdx.x; idx < 16*256; idx += 256) {
        int l = idx >> 8, w = idx & 255;
        float2 v = A[l*257 + w];
        dst[l*256 + w] = sqrtf(v.x*v.x + v.y*v.y);
    }
}

// ---------------- final: out += att2 @ dv + s  (dv from DFT_cl ct 32..63) ----------------
__global__ __launch_bounds__(256) void k_out(const unsigned short* __restrict__ dcl, const float* __restrict__ att2,
                                             const float* __restrict__ sv, float* __restrict__ out) {
    __shared__ __align__(16) float A2ls[1024];
    __shared__ float svls[32];
    int blk = blockIdx.x; int b = blk >> 8, h = blk & 255;
    int tid = threadIdx.x;
    for (int idx = tid; idx < 1024; idx += 256) A2ls[idx] = att2[b*1024 + idx];
    if (tid < 32) svls[tid] = sv[b*32 + tid];
    __syncthreads();
    int px = tid;
    const uint4* dvp = (const uint4*)(dcl + ((((size_t)b*256 + h)*256 + px)*64 + 32));
    uint4 d0 = dvp[0], d1 = dvp[1];
    unsigned u[8] = {d0.x, d0.y, d0.z, d0.w, d1.x, d1.y, d1.z, d1.w};
    float dv[32];
    #pragma unroll
    for (int i = 0; i < 8; ++i) {
        dv[2*i]   = bf2f(u[i] & 0xffffu);
        dv[2*i+1] = bf2f(u[i] >> 16);
    }
    float accv[32];
    #pragma unroll
    for (int c = 0; c < 32; ++c) accv[c] = svls[c];
    #pragma unroll
    for (int q = 0; q < 8; ++q) {
        #pragma unroll
        for (int c = 0; c < 32; ++c) {
            float4 a4 = *(const float4*)&A2ls[c*32 + q*4];
            accv[c] += a4.x*dv[q*4] + a4.y*dv[q*4+1] + a4.z*dv[q*4+2] + a4.w*dv[q*4+3];
        }
    }
    float* ob = out + (size_t)b*CH*HW_ + (size_t)h*256 + px;
    #pragma unroll
    for (int c = 0; c < 32; ++c) ob[(size_t)c*HW_] += accv[c];
}

extern "C" void kernel_launch(void* const* d_in, const int* in_sizes, int n_in,
                              void* d_out, int out_size, void* d_ws, size_t ws_size,
                              hipStream_t stream) {
    const float* x  = (const float*)d_in[0];
    const float* y  = (const float*)d_in[1];
    const float* wq = (const float*)d_in[2];
    const float* bq = (const float*)d_in[3];
    const float* wk = (const float*)d_in[4];
    const float* bk = (const float*)d_in[5];
    const float* wv = (const float*)d_in[6];
    const float* bv = (const float*)d_in[7];
    const float* wd = (const float*)d_in[8];
    const float* bd = (const float*)d_in[9];
    const float* wc = (const float*)d_in[10];
    const float* bc = (const float*)d_in[11];
    const float* wi = (const float*)d_in[12];
    const float* bi = (const float*)d_in[13];
    float* out = (float*)d_out;

    char* ws = (char*)d_ws;
    size_t o = 0;
    float*          R1   = (float*)(ws + o);          o += (size_t)BATCH*CH*HW_*4;    // 33.5 MB
    float2*         CAt  = (float2*)(ws + o);         o += (size_t)BATCH*CH*HW_*8;    // 67 MB (aliased by Z1T)
    unsigned short* FSHc = (unsigned short*)(ws + o); o += (size_t)BATCH*CH2*HW_*2;   // 33.5 MB
    unsigned short* DFTc = (unsigned short*)(ws + o); o += (size_t)BATCH*CH2*HW_*2;   // 33.5 MB
    unsigned short* Gpl  = (unsigned short*)(ws + o); o += (size_t)BATCH*CH2*HW_*2;   // 33.5 MB
    unsigned short* wpk1 = (unsigned short*)(ws + o); o += 9*64*64*2;
    unsigned short* wpk2 = (unsigned short*)(ws + o); o += 9*64*64*2;
    float*          Mb   = (float*)(ws + o);          o += 4096*4;
    float*          Sxb  = (float*)(ws + o);          o += 128*4;
    float*          Sdb  = (float*)(ws + o);          o += 128*4;
    float*          A2b  = (float*)(ws + o);          o += 4096*4;
    float*          Svb  = (float*)(ws + o);          o += 128*4;
    if (ws_size < o) return;

    float2* Z1T = CAt;   // alias: CAt dead after fwd2, Z1T written by inv1 later

    hipMemsetAsync(Mb, 0, (4096 + 128 + 128) * 4, stream);

    k_wpack<<<144, 256, 0, stream>>>(wc, wpk1, 1);   // slot-permuted ic order (matches FSHc)
    k_wpack<<<144, 256, 0, stream>>>(wi, wpk2, 0);   // natural ic order (matches DFTc)
    k_conv1x1<<<1024, 256, 0, stream>>>(y, wd, bd, R1);
    k_fft_fwd1<<<2048, 256, 0, stream>>>(R1, CAt);
    k_fft_fwd2<<<2048, 256, 0, stream>>>(CAt, FSHc);
    k_conv3<0><<<2048, 256, 0, stream>>>(FSHc, wpk1, bc, DFTc);
    k_conv3<1><<<2048, 256, 0, stream>>>(DFTc, wpk2, bi, Gpl);
    k_gram<<<1024, 256, 0, stream>>>(x, DFTc, Mb, Sxb, Sdb);
    k_att<<<1, 256, 0, stream>>>(Mb, Sxb, Sdb, wq, bq, wk, bk, wv, bv, A2b, Svb);
    k_fft_inv1<<<2048, 256, 0, stream>>>(Gpl, Z1T);
    k_fft_inv2<<<2048, 256, 0, stream>>>(Z1T, out);
    k_out<<<1024, 256, 0, stream>>>(DFTc, A2b, Svb, out);
}

// Round 3
// 421.327 us; speedup vs baseline: 3.1276x; 1.1539x over previous
//
#include <hip/hip_runtime.h>
#include <math.h>

#define HW_ (256*256)
#define CH 32
#define CH2 64
#define BATCH 4

typedef short bf16x8 __attribute__((ext_vector_type(8)));
typedef float f32x4 __attribute__((ext_vector_type(4)));

__device__ __forceinline__ unsigned short f2bf(float f) {
    union { float f; unsigned u; } v; v.f = f;
    unsigned r = v.u + 0x7fffu + ((v.u >> 16) & 1u);
    return (unsigned short)(r >> 16);
}
__device__ __forceinline__ float bf2f(unsigned h) {
    union { unsigned u; float f; } v; v.u = h << 16;
    return v.f;
}

// slot -> true channel index for FSH channel-last layout (see k_fft_fwd2)
__device__ __forceinline__ int ctof_slot(int s) {
    return s < 16 ? s + 16 : s < 32 ? s + 32 : s < 48 ? s - 32 : s - 16;
}

// ---------------- FFT core: 16 lines of 256-point radix-2 DIT in LDS ----------------
__device__ __forceinline__ void build_tw(float2* tw, float sign) {
    int tid = threadIdx.x;
    if (tid < 128) {
        float ang = sign * 6.2831853071795864769f * (float)tid / 256.0f;
        float s, c; sincosf(ang, &s, &c);
        tw[tid] = make_float2(c, s);
    }
}

__device__ __forceinline__ void fft_core(float2* A, const float2* tw) {
    const int tid = threadIdx.x;
    for (int idx = tid; idx < 16*256; idx += 256) {
        int l = idx >> 8, i = idx & 255;
        int j = __brev(i) >> 24;
        if (i < j) {
            int base = l*257;
            float2 t = A[base+i]; A[base+i] = A[base+j]; A[base+j] = t;
        }
    }
    __syncthreads();
    for (int s = 1; s <= 8; ++s) {
        int half = 1 << (s-1);
        int shift = 8 - s;
        for (int idx = tid; idx < 16*128; idx += 256) {
            int l = idx >> 7, bf = idx & 127;
            int k = bf & (half-1);
            int g = bf >> (s-1);
            int i0 = l*257 + (g << s) + k;
            int i1 = i0 + half;
            float2 w = tw[k << shift];
            float2 u = A[i0], v = A[i1];
            float tx = v.x*w.x - v.y*w.y;
            float ty = v.x*w.y + v.y*w.x;
            A[i0] = make_float2(u.x + tx, u.y + ty);
            A[i1] = make_float2(u.x - tx, u.y - ty);
        }
        __syncthreads();
    }
}

// ---------------- fwd FFT pass 1: rows; write TRANSPOSED bf16 CAt[bc][w][h] ----------------
__global__ __launch_bounds__(256) void k_fft_fwd1(const float* __restrict__ yd, ushort2* __restrict__ CAt) {
    __shared__ float2 A[16*257];
    __shared__ float2 tw[128];
    build_tw(tw, -1.0f);
    int blk = blockIdx.x;
    int bc = blk >> 4, h0 = (blk & 15) << 4;
    const float sc = 1.0f/16.0f;
    const float* src = yd + (size_t)bc*HW_ + (size_t)h0*256;
    for (int idx = threadIdx.x; idx < 16*256; idx += 256) {
        int l = idx >> 8, w = idx & 255;
        A[l*257 + w] = make_float2(src[l*256 + w]*sc, 0.0f);
    }
    __syncthreads();
    fft_core(A, tw);
    int t = threadIdx.x;           // t = freq index w
    ushort2* dst = CAt + (size_t)bc*HW_ + (size_t)t*256 + h0;
    #pragma unroll
    for (int l = 0; l < 16; ++l) {
        float2 v = A[l*257 + t];
        dst[l] = make_ushort2(f2bf(v.x), f2bf(v.y));   // 64B contiguous per lane
    }
}

// -------- fwd FFT pass 2: block=(b,chalf,w): 16 channels' h-columns; FFT over h;
//          write channel-last bf16 FSH[bt][ht][wt][slot] with fftshift folded in --------
// slot layout per px-row: [0..15]=re(c16..31) [16..31]=im(c16..31)->ct48..63
//                         [32..47]=re(c0..15)->ct0..15 [48..63]=im -> ct32..47
__global__ __launch_bounds__(256) void k_fft_fwd2(const ushort2* __restrict__ CAt, unsigned short* __restrict__ FSH) {
    __shared__ float2 A[16*257];
    __shared__ float2 tw[128];
    build_tw(tw, -1.0f);
    int blk = blockIdx.x;
    int b = blk >> 9, chalf = (blk >> 8) & 1, w = blk & 255;
    const float sc = 1.0f/16.0f;
    const ushort2* src = CAt + (((size_t)(b*32 + chalf*16))*256 + w)*256;
    for (int idx = threadIdx.x; idx < 16*256; idx += 256) {
        int l = idx >> 8, h = idx & 255;
        ushort2 v = src[(size_t)l*HW_ + h];
        A[l*257 + h] = make_float2(bf2f(v.x)*sc, bf2f(v.y)*sc);
    }
    __syncthreads();
    fft_core(A, tw);
    int t = threadIdx.x;           // t = freq index h
    int bt = (b + 2) & 3;
    int ht = (t + 128) & 255;
    int wt = (w + 128) & 255;
    unsigned short pk[32];
    #pragma unroll
    for (int l = 0; l < 16; ++l) {
        float2 v = A[l*257 + t];
        pk[l]      = f2bf(v.x);
        pk[16 + l] = f2bf(v.y);
    }
    unsigned short* dst = FSH + ((((size_t)bt*256 + ht)*256 + wt)*64 + chalf*32);
    uint4* d4 = (uint4*)dst;
    const uint4* s4 = (const uint4*)pk;
    d4[0] = s4[0]; d4[1] = s4[1]; d4[2] = s4[2]; d4[3] = s4[3];
}

// ---------------- weight pre-pack (both conv weights in one launch) ----------------
__global__ __launch_bounds__(256) void k_wpack2(const float* __restrict__ wc, const float* __restrict__ wi,
                                                unsigned short* __restrict__ d1, unsigned short* __restrict__ d2) {
    int i = blockIdx.x*256 + threadIdx.x;      // grid covers 2*36864 exactly
    int half = i >= 36864;
    int j = i - half*36864;
    int tap = j >> 12, rem = j & 4095, oc = rem >> 6, s = rem & 63;
    if (half) {
        d2[j] = f2bf(wi[((size_t)(oc*64 + s))*9 + tap]);
    } else {
        int ic = ctof_slot(s);
        d1[j] = f2bf(wc[((size_t)(oc*64 + ic))*9 + tap]);
    }
}

// ---------------- conv3x3 via MFMA implicit GEMM ----------------
template<int MODE>
__global__ __launch_bounds__(256) void k_conv3(const unsigned short* __restrict__ in_cl,
                                               const unsigned short* __restrict__ wpk,
                                               const float* __restrict__ bias,
                                               unsigned short* __restrict__ outp) {
    __shared__ __align__(16) char XsRaw[3*1040*16];   // [3 rows][130 cols][64 ic] bf16, swizzled
    __shared__ __align__(16) char WsRaw[8192];        // [64 oc][64 ic] bf16, swizzled
    int tid = threadIdx.x;
    int blk = blockIdx.x;
    int wseg = blk & 1, h = (blk >> 1) & 255, b = blk >> 9;
    int w0 = wseg * 128;

    for (int r = 0; r < 3; ++r) {
        int hh = h - 1 + r;
        bool hv = (hh >= 0) && (hh < 256);
        const unsigned short* rowp = in_cl + (((size_t)b*256 + hh)*256)*64;
        for (int gl = tid; gl < 1040; gl += 256) {
            int col = gl >> 3, hseg = gl & 7;
            int wcol = w0 - 1 + col;
            uint4 v = make_uint4(0,0,0,0);
            if (hv && wcol >= 0 && wcol < 256) {
                v = *(const uint4*)(rowp + (size_t)wcol*64 + hseg*8);
                if (MODE == 1) {
                    unsigned* pv = (unsigned*)&v;
                    #pragma unroll
                    for (int q = 0; q < 4; ++q) {
                        unsigned a = pv[q];
                        unsigned lo = a & 0xffffu, hi = a >> 16;
                        if (lo & 0x8000u) lo = 0;
                        if (hi & 0x8000u) hi = 0;
                        pv[q] = lo | (hi << 16);
                    }
                }
            }
            int byte = ((r*1040 + gl) << 4) ^ ((col & 7) << 4);
            *(uint4*)(XsRaw + byte) = v;
        }
    }

    int lane = tid & 63;
    int wv = tid >> 6;
    int l16 = lane & 15, lq = lane >> 4;
    int pxbase = wv * 32;

    f32x4 acc[4][2];
    #pragma unroll
    for (int i = 0; i < 4; ++i)
        #pragma unroll
        for (int j = 0; j < 2; ++j) acc[i][j] = (f32x4)0.0f;

    for (int tap = 0; tap < 9; ++tap) {
        __syncthreads();
        {
            const uint4* wsrc = (const uint4*)(wpk + (size_t)tap*4096);
            #pragma unroll
            for (int q = 0; q < 2; ++q) {
                int g = tid*2 + q;
                int oc = g >> 3;
                int byte = (g << 4) ^ ((oc & 7) << 4);
                *(uint4*)(WsRaw + byte) = wsrc[g];
            }
        }
        __syncthreads();
        int dy = tap / 3, dx = tap - dy*3;
        #pragma unroll
        for (int kk = 0; kk < 2; ++kk) {
            int hseg = kk*4 + lq;
            bf16x8 xf[2], wf[4];
            #pragma unroll
            for (int j = 0; j < 2; ++j) {
                int col = pxbase + j*16 + l16 + dx;
                int byte = ((dy*1040 + col*8 + hseg) << 4) ^ ((col & 7) << 4);
                xf[j] = *(const bf16x8*)(XsRaw + byte);
            }
            #pragma unroll
            for (int i = 0; i < 4; ++i) {
                int oc = i*16 + l16;
                int byte = ((oc*8 + hseg) << 4) ^ ((oc & 7) << 4);
                wf[i] = *(const bf16x8*)(WsRaw + byte);
                #pragma unroll
                for (int j = 0; j < 2; ++j) {
                    if (MODE == 0)
                        acc[i][j] = __builtin_amdgcn_mfma_f32_16x16x32_bf16(wf[i], xf[j], acc[i][j], 0, 0, 0);
                    else
                        acc[i][j] = __builtin_amdgcn_mfma_f32_16x16x32_bf16(xf[j], wf[i], acc[i][j], 0, 0, 0);
                }
            }
        }
    }

    if (MODE == 0) {
        #pragma unroll
        for (int j = 0; j < 2; ++j) {
            int px = w0 + pxbase + j*16 + l16;
            unsigned short* orow = outp + (((size_t)b*256 + h)*256 + px)*64;
            #pragma unroll
            for (int i = 0; i < 4; ++i) {
                int oc0 = i*16 + lq*4;
                float4 bv = *(const float4*)(bias + oc0);
                unsigned short c0 = f2bf(acc[i][j][0] + bv.x);
                unsigned short c1 = f2bf(acc[i][j][1] + bv.y);
                unsigned short c2 = f2bf(acc[i][j][2] + bv.z);
                unsigned short c3 = f2bf(acc[i][j][3] + bv.w);
                uint2 u;
                u.x = (unsigned)c0 | ((unsigned)c1 << 16);
                u.y = (unsigned)c2 | ((unsigned)c3 << 16);
                *(uint2*)(orow + oc0) = u;
            }
        }
    } else {
        #pragma unroll
        for (int i = 0; i < 4; ++i) {
            int oc = i*16 + l16;
            float bv = bias[oc];
            unsigned short* oplane = outp + ((size_t)b*64 + oc)*HW_ + (size_t)h*256;
            #pragma unroll
            for (int j = 0; j < 2; ++j) {
                int px0 = w0 + pxbase + j*16 + lq*4;
                unsigned short c0 = f2bf(acc[i][j][0] + bv);
                unsigned short c1 = f2bf(acc[i][j][1] + bv);
                unsigned short c2 = f2bf(acc[i][j][2] + bv);
                unsigned short c3 = f2bf(acc[i][j][3] + bv);
                uint2 u;
                u.x = (unsigned)c0 | ((unsigned)c1 << 16);
                u.y = (unsigned)c2 | ((unsigned)c3 << 16);
                *(uint2*)(oplane + px0) = u;
            }
        }
    }
}

// ---------------- conv1x1 (fp32) ----------------
__global__ __launch_bounds__(256) void k_conv1x1(const float* __restrict__ in, const float* __restrict__ w,
                                                 const float* __restrict__ bias, float* __restrict__ out) {
    __shared__ float ts[32*257];
    int blk = blockIdx.x; int b = blk >> 8, h = blk & 255;
    int tid = threadIdx.x;
    const float* src = in + (size_t)b*CH*HW_ + (size_t)h*256;
    for (int idx = tid; idx < 32*256; idx += 256) {
        int c = idx >> 8, ww = idx & 255;
        ts[c*257 + ww] = src[(size_t)c*HW_ + ww];
    }
    __syncthreads();
    float acc[32];
    #pragma unroll
    for (int o = 0; o < 32; ++o) acc[o] = bias[o];
    for (int c = 0; c < 32; ++c) {
        float v = ts[c*257 + tid];
        #pragma unroll
        for (int o = 0; o < 32; ++o) acc[o] += w[o*32 + c] * v;
    }
    float* dst = out + (size_t)b*CH*HW_ + (size_t)h*256 + tid;
    #pragma unroll
    for (int o = 0; o < 32; ++o) dst[(size_t)o*HW_] = acc[o];
}

// ---------------- Gram via MFMA: Mpart[b][chunk][a][e] = sum_px x[a,px]*dk[px,e] ----------------
// grid: 4 batches x 128 chunks; block 256 thr / 4 waves; wave covers 128 px.
__global__ __launch_bounds__(256) void k_gram(const float* __restrict__ x, const unsigned short* __restrict__ dcl,
                                              float* __restrict__ Mpart, float* __restrict__ Sxp, float* __restrict__ Sdp) {
    __shared__ float mred[1024];
    __shared__ float sxred[32];
    __shared__ float sdred[32];
    int blk = blockIdx.x;
    int b = blk >> 7, chunk = blk & 127;
    int tid = threadIdx.x, lane = tid & 63, wv = tid >> 6;
    int l16 = lane & 15, lq = lane >> 4;
    for (int idx = tid; idx < 1024; idx += 256) mred[idx] = 0.0f;
    if (tid < 32) { sxred[tid] = 0.0f; sdred[tid] = 0.0f; }
    __syncthreads();

    const float* xb0 = x + (size_t)b*CH*HW_ + (size_t)l16*HW_;
    const float* xb1 = xb0 + (size_t)16*HW_;
    const unsigned short* db = dcl + (size_t)b*HW_*64;

    f32x4 acc[2][2];
    #pragma unroll
    for (int i = 0; i < 2; ++i)
        #pragma unroll
        for (int j = 0; j < 2; ++j) acc[i][j] = (f32x4)0.0f;
    float sx0 = 0, sx1 = 0, sd0 = 0, sd1 = 0;

    int pxw = chunk*512 + wv*128;
    #pragma unroll
    for (int ks = 0; ks < 4; ++ks) {
        int px = pxw + ks*32 + lq*8;
        float4 xa = *(const float4*)(xb0 + px);
        float4 xc = *(const float4*)(xb0 + px + 4);
        float4 ya = *(const float4*)(xb1 + px);
        float4 yc = *(const float4*)(xb1 + px + 4);
        bf16x8 a0, a1, b0, b1;
        const float* pxa = (const float*)&xa;
        const float* pxc = (const float*)&xc;
        const float* pya = (const float*)&ya;
        const float* pyc = (const float*)&yc;
        #pragma unroll
        for (int j = 0; j < 4; ++j) {
            a0[j]   = (short)f2bf(pxa[j]);  sx0 += pxa[j];
            a0[4+j] = (short)f2bf(pxc[j]);  sx0 += pxc[j];
            a1[j]   = (short)f2bf(pya[j]);  sx1 += pya[j];
            a1[4+j] = (short)f2bf(pyc[j]);  sx1 += pyc[j];
        }
        const unsigned short* dbp = db + (size_t)px*64 + l16;
        #pragma unroll
        for (int j = 0; j < 8; ++j) {
            unsigned short v0 = dbp[j*64];
            unsigned short v1 = dbp[j*64 + 16];
            b0[j] = (short)v0;  sd0 += bf2f(v0);
            b1[j] = (short)v1;  sd1 += bf2f(v1);
        }
        acc[0][0] = __builtin_amdgcn_mfma_f32_16x16x32_bf16(a0, b0, acc[0][0], 0, 0, 0);
        acc[0][1] = __builtin_amdgcn_mfma_f32_16x16x32_bf16(a0, b1, acc[0][1], 0, 0, 0);
        acc[1][0] = __builtin_amdgcn_mfma_f32_16x16x32_bf16(a1, b0, acc[1][0], 0, 0, 0);
        acc[1][1] = __builtin_amdgcn_mfma_f32_16x16x32_bf16(a1, b1, acc[1][1], 0, 0, 0);
    }

    // cross-wave reduce into LDS
    #pragma unroll
    for (int fi = 0; fi < 2; ++fi)
        #pragma unroll
        for (int fj = 0; fj < 2; ++fj)
            #pragma unroll
            for (int r = 0; r < 4; ++r)
                atomicAdd(&mred[(fi*16 + lq*4 + r)*32 + fj*16 + l16], acc[fi][fj][r]);

    // row/col sums: reduce over lq (lanes l16, l16+16, l16+32, l16+48)
    sx0 += __shfl_xor(sx0, 16); sx0 += __shfl_xor(sx0, 32);
    sx1 += __shfl_xor(sx1, 16); sx1 += __shfl_xor(sx1, 32);
    sd0 += __shfl_xor(sd0, 16); sd0 += __shfl_xor(sd0, 32);
    sd1 += __shfl_xor(sd1, 16); sd1 += __shfl_xor(sd1, 32);
    if (lane < 16) {
        atomicAdd(&sxred[l16], sx0);
        atomicAdd(&sxred[l16 + 16], sx1);
        atomicAdd(&sdred[l16], sd0);
        atomicAdd(&sdred[l16 + 16], sd1);
    }
    __syncthreads();

    float* mp = Mpart + ((size_t)(b*128 + chunk))*1024;
    for (int idx = tid; idx < 1024; idx += 256) mp[idx] = mred[idx];
    if (tid < 32) {
        Sxp[(b*128 + chunk)*32 + tid] = sxred[tid];
        Sdp[(b*128 + chunk)*32 + tid] = sdred[tid];
    }
}

// ---------------- reduce partials -> M, Sx, Sdk ----------------
__global__ __launch_bounds__(256) void k_reduce(const float* __restrict__ Mpart, const float* __restrict__ Sxp,
                                                const float* __restrict__ Sdp,
                                                float* __restrict__ M, float* __restrict__ Sx, float* __restrict__ Sdk) {
    int b = blockIdx.x >> 2, seg = blockIdx.x & 3;
    int o = seg*256 + threadIdx.x;
    float s = 0;
    for (int c = 0; c < 128; ++c) s += Mpart[((size_t)(b*128 + c))*1024 + o];
    M[b*1024 + o] = s;
    if (seg == 0) {
        if (threadIdx.x < 32) {
            float t = 0;
            for (int c = 0; c < 128; ++c) t += Sxp[(b*128 + c)*32 + threadIdx.x];
            Sx[b*32 + threadIdx.x] = t;
        } else if (threadIdx.x < 64) {
            int e = threadIdx.x - 32;
            float t = 0;
            for (int c = 0; c < 128; ++c) t += Sdp[(b*128 + c)*32 + e];
            Sdk[b*32 + e] = t;
        }
    }
}

// ---------------- tiny attention ----------------
__global__ __launch_bounds__(256) void k_att(const float* __restrict__ M, const float* __restrict__ Sx,
                                              const float* __restrict__ Sdk,
                                              const float* __restrict__ wq, const float* __restrict__ bq,
                                              const float* __restrict__ wk, const float* __restrict__ bk,
                                              const float* __restrict__ wv, const float* __restrict__ bv,
                                              float* __restrict__ att2, float* __restrict__ sout) {
    __shared__ float Mls[1024], T1[1024], attls[32*33];
    __shared__ float wqs[1024], wks[1024], wvs[1024];
    __shared__ float q1[32], k1[32];
    int tid = threadIdx.x;
    for (int idx = tid; idx < 1024; idx += 256) { wqs[idx] = wq[idx]; wks[idx] = wk[idx]; wvs[idx] = wv[idx]; }
    __syncthreads();
    for (int b = 0; b < 4; ++b) {
        for (int idx = tid; idx < 1024; idx += 256) Mls[idx] = M[b*1024 + idx];
        __syncthreads();
        if (tid < 32) { float s=0; for (int a=0;a<32;++a) s += wqs[tid*32+a]*Sx[b*32+a]; q1[tid]=s; }
        else if (tid < 64) { int d=tid-32; float s=0; for (int e=0;e<32;++e) s += wks[d*32+e]*Sdk[b*32+e]; k1[d]=s; }
        for (int idx = tid; idx < 1024; idx += 256) {
            int c = idx >> 5, e = idx & 31;
            float s = 0;
            for (int a=0;a<32;++a) s += wqs[c*32+a]*Mls[a*32+e];
            T1[idx] = s;
        }
        __syncthreads();
        for (int idx = tid; idx < 1024; idx += 256) {
            int c = idx >> 5, d = idx & 31;
            float s = 0;
            for (int e=0;e<32;++e) s += T1[c*32+e]*wks[d*32+e];
            s += bq[c]*k1[d] + bk[d]*q1[c] + 65536.0f*bq[c]*bk[d];
            attls[c*33+d] = s;
        }
        __syncthreads();
        if (tid < 32) {
            int d = tid;
            float mx = -1e30f;
            for (int c=0;c<32;++c) mx = fmaxf(mx, attls[c*33+d]);
            float sum = 0;
            for (int c=0;c<32;++c) { float e_ = expf(attls[c*33+d]-mx); attls[c*33+d]=e_; sum+=e_; }
            float inv = 1.0f/sum;
            for (int c=0;c<32;++c) attls[c*33+d] *= inv;
        }
        __syncthreads();
        for (int idx = tid; idx < 1024; idx += 256) {
            int c = idx >> 5, e = idx & 31;
            float s = 0;
            for (int d=0; d<32; ++d) s += attls[c*33+d]*wvs[d*32+e];
            att2[b*1024 + idx] = s;
        }
        if (tid < 32) {
            float s=0; for (int d=0;d<32;++d) s += attls[tid*33+d]*bv[d];
            sout[b*32+tid] = s;
        }
        __syncthreads();
    }
}

// ---------------- inv FFT pass 1: columns, ifftshift gather from planar bf16 G ----------------
__global__ __launch_bounds__(256) void k_fft_inv1(const unsigned short* __restrict__ G, ushort2* __restrict__ Z1T) {
    __shared__ float2 A[16*257];
    __shared__ float2 tw[128];
    build_tw(tw, 1.0f);
    int blk = blockIdx.x;
    int bc = blk >> 4, w0 = (blk & 15) << 4;
    int b = bc >> 5, c = bc & 31;
    int bs = (b + 2) & 3;
    const float sc = 1.0f/16.0f;
    const unsigned short* gre = G + ((size_t)(bs*CH2 + c + 32))*HW_;
    const unsigned short* gim = G + ((size_t)(bs*CH2 + c))*HW_;
    for (int idx = threadIdx.x; idx < 16*256; idx += 256) {
        int h = idx >> 4, l = idx & 15;
        int hs = (h + 128) & 255;
        int ws = (w0 + l + 128) & 255;
        A[l*257 + h] = make_float2(bf2f(gre[(size_t)hs*256 + ws])*sc, bf2f(gim[(size_t)hs*256 + ws])*sc);
    }
    __syncthreads();
    fft_core(A, tw);
    ushort2* dst = Z1T + (size_t)bc*HW_;
    for (int idx = threadIdx.x; idx < 16*256; idx += 256) {
        int l = idx >> 8, h = idx & 255;
        float2 v = A[l*257 + h];
        dst[(size_t)(w0 + l)*256 + h] = make_ushort2(f2bf(v.x), f2bf(v.y));
    }
}

// ---------------- inv FFT pass 2: rows, abs -> out ----------------
__global__ __launch_bounds__(256) void k_fft_inv2(const ushort2* __restrict__ Z1T, float* __restrict__ out) {
    __shared__ float2 A[16*257];
    __shared__ float2 tw[128];
    build_tw(tw, 1.0f);
    int blk = blockIdx.x;
    int bc = blk >> 4, h0 = (blk & 15) << 4;
    const float sc = 1.0f/16.0f;
    const ushort2* src = Z1T + (size_t)bc*HW_ + h0;
    for (int idx = threadIdx.x; idx < 16*256; idx += 256) {
        int w = idx >> 4, l = idx & 15;
        ushort2 v = src[(size_t)w*256 + l];
        A[l*257 + w] = make_float2(bf2f(v.x)*sc, bf2f(v.y)*sc);
    }
    __syncthreads();
    fft_core(A, tw);
    float* dst = out + (size_t)bc*HW_ + (size_t)h0*256;
    for (int idx = threadIdx.x; idx < 16*256; idx += 256) {
        int l = idx >> 8, w = idx & 255;
        float2 v = A[l*257 + w];
        dst[l*256 + w] = sqrtf(v.x*v.x + v.y*v.y);
    }
}

// ---------------- final: out += att2 @ dv + s  (dv from DFT_cl ct 32..63) ----------------
__global__ __launch_bounds__(256) void k_out(const unsigned short* __restrict__ dcl, const float* __restrict__ att2,
                                             const float* __restrict__ sv, float* __restrict__ out) {
    __shared__ __align__(16) float A2ls[1024];
    __shared__ float svls[32];
    int blk = blockIdx.x; int b = blk >> 8, h = blk & 255;
    int tid = threadIdx.x;
    for (int idx = tid; idx < 1024; idx += 256) A2ls[idx] = att2[b*1024 + idx];
    if (tid < 32) svls[tid] = sv[b*32 + tid];
    __syncthreads();
    int px = tid;
    const uint4* dvp = (const uint4*)(dcl + ((((size_t)b*256 + h)*256 + px)*64 + 32));
    uint4 d0 = dvp[0], d1 = dvp[1];
    unsigned u[8] = {d0.x, d0.y, d0.z, d0.w, d1.x, d1.y, d1.z, d1.w};
    float dv[32];
    #pragma unroll
    for (int i = 0; i < 8; ++i) {
        dv[2*i]   = bf2f(u[i] & 0xffffu);
        dv[2*i+1] = bf2f(u[i] >> 16);
    }
    float accv[32];
    #pragma unroll
    for (int c = 0; c < 32; ++c) accv[c] = svls[c];
    #pragma unroll
    for (int q = 0; q < 8; ++q) {
        #pragma unroll
        for (int c = 0; c < 32; ++c) {
            float4 a4 = *(const float4*)&A2ls[c*32 + q*4];
            accv[c] += a4.x*dv[q*4] + a4.y*dv[q*4+1] + a4.z*dv[q*4+2] + a4.w*dv[q*4+3];
        }
    }
    float* ob = out + (size_t)b*CH*HW_ + (size_t)h*256 + px;
    #pragma unroll
    for (int c = 0; c < 32; ++c) ob[(size_t)c*HW_] += accv[c];
}

extern "C" void kernel_launch(void* const* d_in, const int* in_sizes, int n_in,
                              void* d_out, int out_size, void* d_ws, size_t ws_size,
                              hipStream_t stream) {
    const float* x  = (const float*)d_in[0];
    const float* y  = (const float*)d_in[1];
    const float* wq = (const float*)d_in[2];
    const float* bq = (const float*)d_in[3];
    const float* wk = (const float*)d_in[4];
    const float* bk = (const float*)d_in[5];
    const float* wv = (const float*)d_in[6];
    const float* bv = (const float*)d_in[7];
    const float* wd = (const float*)d_in[8];
    const float* bd = (const float*)d_in[9];
    const float* wc = (const float*)d_in[10];
    const float* bc = (const float*)d_in[11];
    const float* wi = (const float*)d_in[12];
    const float* bi = (const float*)d_in[13];
    float* out = (float*)d_out;

    char* ws = (char*)d_ws;
    size_t o = 0;
    float*          R1   = (float*)(ws + o);          o += (size_t)BATCH*CH*HW_*4;    // 33.5 MB
    ushort2*        CAt  = (ushort2*)(ws + o);        o += (size_t)BATCH*CH*HW_*4;    // 33.5 MB (aliased by Z1T)
    unsigned short* FSHc = (unsigned short*)(ws + o); o += (size_t)BATCH*CH2*HW_*2;   // 33.5 MB
    unsigned short* DFTc = (unsigned short*)(ws + o); o += (size_t)BATCH*CH2*HW_*2;   // 33.5 MB
    unsigned short* Gpl  = (unsigned short*)(ws + o); o += (size_t)BATCH*CH2*HW_*2;   // 33.5 MB
    unsigned short* wpk1 = (unsigned short*)(ws + o); o += 9*64*64*2;
    unsigned short* wpk2 = (unsigned short*)(ws + o); o += 9*64*64*2;
    float*          Mpart= (float*)(ws + o);          o += (size_t)512*1024*4;        // 2 MB
    float*          Sxp  = (float*)(ws + o);          o += 512*32*4;
    float*          Sdp  = (float*)(ws + o);          o += 512*32*4;
    float*          Mb   = (float*)(ws + o);          o += 4096*4;
    float*          Sxb  = (float*)(ws + o);          o += 128*4;
    float*          Sdb  = (float*)(ws + o);          o += 128*4;
    float*          A2b  = (float*)(ws + o);          o += 4096*4;
    float*          Svb  = (float*)(ws + o);          o += 128*4;
    if (ws_size < o) return;

    ushort2* Z1T = CAt;   // alias: CAt dead after fwd2, Z1T written by inv1 later

    k_wpack2<<<288, 256, 0, stream>>>(wc, wi, wpk1, wpk2);
    k_conv1x1<<<1024, 256, 0, stream>>>(y, wd, bd, R1);
    k_fft_fwd1<<<2048, 256, 0, stream>>>(R1, CAt);
    k_fft_fwd2<<<2048, 256, 0, stream>>>(CAt, FSHc);
    k_conv3<0><<<2048, 256, 0, stream>>>(FSHc, wpk1, bc, DFTc);
    k_conv3<1><<<2048, 256, 0, stream>>>(DFTc, wpk2, bi, Gpl);
    k_gram<<<512, 256, 0, stream>>>(x, DFTc, Mpart, Sxp, Sdp);
    k_reduce<<<16, 256, 0, stream>>>(Mpart, Sxp, Sdp, Mb, Sxb, Sdb);
    k_att<<<1, 256, 0, stream>>>(Mb, Sxb, Sdb, wq, bq, wk, bk, wv, bv, A2b, Svb);
    k_fft_inv1<<<2048, 256, 0, stream>>>(Gpl, Z1T);
    k_fft_inv2<<<2048, 256, 0, stream>>>(Z1T, out);
    k_out<<<1024, 256, 0, stream>>>(DFTc, A2b, Svb, out);
}

// Round 4
// 284.617 us; speedup vs baseline: 4.6298x; 1.4803x over previous
//
#include <hip/hip_runtime.h>
#include <math.h>

#define HW_ (256*256)
#define CH 32
#define CH2 64
#define BATCH 4

typedef short bf16x8 __attribute__((ext_vector_type(8)));
typedef float f32x4 __attribute__((ext_vector_type(4)));

__device__ __forceinline__ unsigned short f2bf(float f) {
    union { float f; unsigned u; } v; v.f = f;
    unsigned r = v.u + 0x7fffu + ((v.u >> 16) & 1u);
    return (unsigned short)(r >> 16);
}
__device__ __forceinline__ float bf2f(unsigned h) {
    union { unsigned u; float f; } v; v.u = h << 16;
    return v.f;
}

// slot -> true channel index for FSH channel-last layout (see k_fft_fwd2)
__device__ __forceinline__ int ctof_slot(int s) {
    return s < 16 ? s + 16 : s < 32 ? s + 32 : s < 48 ? s - 32 : s - 16;
}

// ---------------- FFT core: 16 lines of 256-point radix-4 DIT in LDS ----------------
// tw[k] = exp(sign*2*pi*i*k/256), k<256 (2KB LDS)
__device__ __forceinline__ void build_tw4(float2* tw, float sign) {
    int tid = threadIdx.x;
    float ang = sign * 6.2831853071795864769f * (float)tid / 256.0f;
    float s, c; sincosf(ang, &s, &c);
    tw[tid] = make_float2(c, s);
}

__device__ __forceinline__ int rev4_8(int i) {
    return ((i & 3) << 6) | ((i & 12) << 2) | ((i & 48) >> 2) | (i >> 6);
}

__device__ __forceinline__ float2 cmul(float2 a, float2 b) {
    return make_float2(a.x*b.x - a.y*b.y, a.x*b.y + a.y*b.x);
}

// SGN = -1 forward, +1 inverse. Lane mapping l=idx&15 keeps all stages at the
// LDS bank-conflict floor (4 words/bank for b64).
template<int SGN>
__device__ __forceinline__ void fft_core4(float2* A, const float2* tw) {
    const int tid = threadIdx.x;
    // base-4 digit-reverse permutation
    for (int idx = tid; idx < 16*256; idx += 256) {
        int l = idx & 15, i = idx >> 4;
        int j = rev4_8(i);
        if (i < j) {
            int base = l*257;
            float2 t = A[base+i]; A[base+i] = A[base+j]; A[base+j] = t;
        }
    }
    __syncthreads();
    #pragma unroll
    for (int st = 0; st < 4; ++st) {
        const int lq2 = 2*st;
        const int q = 1 << lq2;          // 1,4,16,64
        const int estep = 64 >> lq2;     // 64,16,4,1
        for (int idx = tid; idx < 16*64; idx += 256) {
            int l = idx & 15, bf = idx >> 4;
            int j = bf & (q-1);
            int g = bf >> lq2;
            int base = l*257 + (g << (lq2+2)) + j;
            float2 x0 = A[base];
            float2 x1 = A[base + q];
            float2 x2 = A[base + 2*q];
            float2 x3 = A[base + 3*q];
            if (st > 0) {
                int e = j * estep;
                x1 = cmul(x1, tw[e]);
                x2 = cmul(x2, tw[2*e]);
                x3 = cmul(x3, tw[3*e]);
            }
            float2 t0 = make_float2(x0.x + x2.x, x0.y + x2.y);
            float2 t1 = make_float2(x0.x - x2.x, x0.y - x2.y);
            float2 t2 = make_float2(x1.x + x3.x, x1.y + x3.y);
            float2 t3 = make_float2(x1.x - x3.x, x1.y - x3.y);
            float2 r  = make_float2(-SGN * t3.y, SGN * t3.x);   // SGN*i*t3
            A[base]       = make_float2(t0.x + t2.x, t0.y + t2.y);
            A[base + q]   = make_float2(t1.x + r.x, t1.y + r.y);
            A[base + 2*q] = make_float2(t0.x - t2.x, t0.y - t2.y);
            A[base + 3*q] = make_float2(t1.x - r.x, t1.y - r.y);
        }
        __syncthreads();
    }
}

// ---------------- fwd FFT pass 1: rows; write TRANSPOSED bf16 CAt[bc][w][h] ----------------
__global__ __launch_bounds__(256) void k_fft_fwd1(const unsigned short* __restrict__ yd, ushort2* __restrict__ CAt) {
    __shared__ float2 A[16*257];
    __shared__ float2 tw[256];
    build_tw4(tw, -1.0f);
    int blk = blockIdx.x;
    int bc = blk >> 4, h0 = (blk & 15) << 4;
    const float sc = 1.0f/16.0f;
    const unsigned short* src = yd + (size_t)bc*HW_ + (size_t)h0*256;
    for (int idx = threadIdx.x; idx < 16*256; idx += 256) {
        int l = idx >> 8, w = idx & 255;
        A[l*257 + w] = make_float2(bf2f(src[l*256 + w])*sc, 0.0f);
    }
    __syncthreads();
    fft_core4<-1>(A, tw);
    int t = threadIdx.x;           // t = freq index w
    ushort2* dst = CAt + (size_t)bc*HW_ + (size_t)t*256 + h0;
    #pragma unroll
    for (int l = 0; l < 16; ++l) {
        float2 v = A[l*257 + t];
        dst[l] = make_ushort2(f2bf(v.x), f2bf(v.y));   // 64B contiguous per lane
    }
}

// -------- fwd FFT pass 2: block=(b,chalf,w): 16 channels' h-columns; FFT over h;
//          write channel-last bf16 FSH[bt][ht][wt][slot] with fftshift folded in --------
__global__ __launch_bounds__(256) void k_fft_fwd2(const ushort2* __restrict__ CAt, unsigned short* __restrict__ FSH) {
    __shared__ float2 A[16*257];
    __shared__ float2 tw[256];
    build_tw4(tw, -1.0f);
    int blk = blockIdx.x;
    int b = blk >> 9, chalf = (blk >> 8) & 1, w = blk & 255;
    const float sc = 1.0f/16.0f;
    const ushort2* src = CAt + (((size_t)(b*32 + chalf*16))*256 + w)*256;
    for (int idx = threadIdx.x; idx < 16*256; idx += 256) {
        int l = idx >> 8, h = idx & 255;
        ushort2 v = src[(size_t)l*HW_ + h];
        A[l*257 + h] = make_float2(bf2f(v.x)*sc, bf2f(v.y)*sc);
    }
    __syncthreads();
    fft_core4<-1>(A, tw);
    int t = threadIdx.x;           // t = freq index h
    int bt = (b + 2) & 3;
    int ht = (t + 128) & 255;
    int wt = (w + 128) & 255;
    unsigned short pk[32];
    #pragma unroll
    for (int l = 0; l < 16; ++l) {
        float2 v = A[l*257 + t];
        pk[l]      = f2bf(v.x);
        pk[16 + l] = f2bf(v.y);
    }
    unsigned short* dst = FSH + ((((size_t)bt*256 + ht)*256 + wt)*64 + chalf*32);
    uint4* d4 = (uint4*)dst;
    const uint4* s4 = (const uint4*)pk;
    d4[0] = s4[0]; d4[1] = s4[1]; d4[2] = s4[2]; d4[3] = s4[3];
}

// ---------------- weight pre-pack (both conv weights in one launch) ----------------
__global__ __launch_bounds__(256) void k_wpack2(const float* __restrict__ wc, const float* __restrict__ wi,
                                                unsigned short* __restrict__ d1, unsigned short* __restrict__ d2) {
    int i = blockIdx.x*256 + threadIdx.x;      // grid covers 2*36864 exactly
    int half = i >= 36864;
    int j = i - half*36864;
    int tap = j >> 12, rem = j & 4095, oc = rem >> 6, s = rem & 63;
    if (half) {
        d2[j] = f2bf(wi[((size_t)(oc*64 + s))*9 + tap]);
    } else {
        int ic = ctof_slot(s);
        d1[j] = f2bf(wc[((size_t)(oc*64 + ic))*9 + tap]);
    }
}

// ---------------- conv3x3 via MFMA implicit GEMM, 4 rows x 64 px per block ----------------
// X ring buffer [4 slots][66 cols][64 ic] bf16 swizzled; W [3 taps][64 oc][64 ic] per dy.
// 5 barriers/block. MODE 0: channel-last out; MODE 1: planar out, relu on input.
template<int MODE>
__global__ __launch_bounds__(256) void k_conv3(const unsigned short* __restrict__ in_cl,
                                               const unsigned short* __restrict__ wpk,
                                               const float* __restrict__ bias,
                                               unsigned short* __restrict__ outp) {
    __shared__ __align__(16) char Xs[2112*16];   // 33,792 B
    __shared__ __align__(16) char Ws[1536*16];   // 24,576 B
    int tid = threadIdx.x;
    int blk = blockIdx.x;
    int wseg = blk & 3, hg = (blk >> 2) & 63, b = blk >> 8;
    int h0 = hg*4, w0 = wseg*64;

    const uint4* wsrc = (const uint4*)wpk;

    // ---- initial stage: X rows h0-1..h0+2 (slots 0..3) + W dy=0 ----
    for (int gl = tid; gl < 2112; gl += 256) {
        int slot = gl / 528;
        int rem  = gl - slot*528;
        int col  = rem >> 3, hseg = rem & 7;
        int hh = h0 - 1 + slot;
        int wcol = w0 - 1 + col;
        uint4 v = make_uint4(0,0,0,0);
        if (hh >= 0 && hh < 256 && wcol >= 0 && wcol < 256) {
            v = *(const uint4*)(in_cl + (((size_t)(b*256 + hh)*256 + wcol)*64) + hseg*8);
            if (MODE == 1) {
                unsigned* pv = (unsigned*)&v;
                #pragma unroll
                for (int q = 0; q < 4; ++q) {
                    unsigned a = pv[q];
                    unsigned lo = a & 0xffffu, hi = a >> 16;
                    if (lo & 0x8000u) lo = 0;
                    if (hi & 0x8000u) hi = 0;
                    pv[q] = lo | (hi << 16);
                }
            }
        }
        *(uint4*)(Xs + ((gl << 4) ^ ((col & 7) << 4))) = v;
    }
    for (int gw = tid; gw < 1536; gw += 256) {
        int oc = (gw >> 3) & 63;
        *(uint4*)(Ws + ((gw << 4) ^ ((oc & 7) << 4))) = wsrc[gw];
    }
    __syncthreads();

    int lane = tid & 63;
    int wv = tid >> 6;                 // wave id = output row within block
    int l16 = lane & 15, lq = lane >> 4;

    f32x4 acc[4][4];
    #pragma unroll
    for (int i = 0; i < 4; ++i)
        #pragma unroll
        for (int j = 0; j < 4; ++j) acc[i][j] = (f32x4)0.0f;

    for (int dy = 0; dy < 3; ++dy) {
        if (dy > 0) {
            __syncthreads();
            // stage X row h0-1+(dy+3) into slot (dy+3)&3 = (dy-1)&3
            int k = dy + 3;
            int slot = k & 3;
            int hh = h0 - 1 + k;
            bool hv = hh < 256;
            for (int gl = tid; gl < 528; gl += 256) {
                int col = gl >> 3, hseg = gl & 7;
                int wcol = w0 - 1 + col;
                uint4 v = make_uint4(0,0,0,0);
                if (hv && wcol >= 0 && wcol < 256) {
                    v = *(const uint4*)(in_cl + (((size_t)(b*256 + hh)*256 + wcol)*64) + hseg*8);
                    if (MODE == 1) {
                        unsigned* pv = (unsigned*)&v;
                        #pragma unroll
                        for (int q = 0; q < 4; ++q) {
                            unsigned a = pv[q];
                            unsigned lo = a & 0xffffu, hi = a >> 16;
                            if (lo & 0x8000u) lo = 0;
                            if (hi & 0x8000u) hi = 0;
                            pv[q] = lo | (hi << 16);
                        }
                    }
                }
                int g = slot*528 + gl;
                *(uint4*)(Xs + ((g << 4) ^ ((col & 7) << 4))) = v;
            }
            // stage W for this dy (taps dy*3 .. dy*3+2)
            for (int gw = tid; gw < 1536; gw += 256) {
                int oc = (gw >> 3) & 63;
                *(uint4*)(Ws + ((gw << 4) ^ ((oc & 7) << 4))) = wsrc[dy*1536 + gw];
            }
            __syncthreads();
        }
        int slot = (wv + dy) & 3;
        #pragma unroll
        for (int dx = 0; dx < 3; ++dx) {
            #pragma unroll
            for (int kk = 0; kk < 2; ++kk) {
                int hseg = kk*4 + lq;
                bf16x8 xf[4], wf[4];
                #pragma unroll
                for (int j = 0; j < 4; ++j) {
                    int col = j*16 + l16 + dx;
                    int g = slot*528 + col*8 + hseg;
                    xf[j] = *(const bf16x8*)(Xs + ((g << 4) ^ ((col & 7) << 4)));
                }
                #pragma unroll
                for (int i = 0; i < 4; ++i) {
                    int oc = i*16 + l16;
                    int lw = dx*512 + oc*8 + hseg;
                    wf[i] = *(const bf16x8*)(Ws + ((lw << 4) ^ ((oc & 7) << 4)));
                    #pragma unroll
                    for (int j = 0; j < 4; ++j) {
                        if (MODE == 0)
                            acc[i][j] = __builtin_amdgcn_mfma_f32_16x16x32_bf16(wf[i], xf[j], acc[i][j], 0, 0, 0);
                        else
                            acc[i][j] = __builtin_amdgcn_mfma_f32_16x16x32_bf16(xf[j], wf[i], acc[i][j], 0, 0, 0);
                    }
                }
            }
        }
    }

    int h = h0 + wv;
    if (MODE == 0) {
        // D[m=oc = i*16+lq*4+r][n=px = j*16+l16] -> channel-last
        #pragma unroll
        for (int j = 0; j < 4; ++j) {
            int px = w0 + j*16 + l16;
            unsigned short* orow = outp + (((size_t)b*256 + h)*256 + px)*64;
            #pragma unroll
            for (int i = 0; i < 4; ++i) {
                int oc0 = i*16 + lq*4;
                float4 bv = *(const float4*)(bias + oc0);
                unsigned short c0 = f2bf(acc[i][j][0] + bv.x);
                unsigned short c1 = f2bf(acc[i][j][1] + bv.y);
                unsigned short c2 = f2bf(acc[i][j][2] + bv.z);
                unsigned short c3 = f2bf(acc[i][j][3] + bv.w);
                uint2 u;
                u.x = (unsigned)c0 | ((unsigned)c1 << 16);
                u.y = (unsigned)c2 | ((unsigned)c3 << 16);
                *(uint2*)(orow + oc0) = u;
            }
        }
    } else {
        // D[m=px = j*16+lq*4+r][n=oc = i*16+l16] -> planar
        #pragma unroll
        for (int i = 0; i < 4; ++i) {
            int oc = i*16 + l16;
            float bv = bias[oc];
            unsigned short* oplane = outp + ((size_t)b*64 + oc)*HW_ + (size_t)h*256;
            #pragma unroll
            for (int j = 0; j < 4; ++j) {
                int px0 = w0 + j*16 + lq*4;
                unsigned short c0 = f2bf(acc[i][j][0] + bv);
                unsigned short c1 = f2bf(acc[i][j][1] + bv);
                unsigned short c2 = f2bf(acc[i][j][2] + bv);
                unsigned short c3 = f2bf(acc[i][j][3] + bv);
                uint2 u;
                u.x = (unsigned)c0 | ((unsigned)c1 << 16);
                u.y = (unsigned)c2 | ((unsigned)c3 << 16);
                *(uint2*)(oplane + px0) = u;
            }
        }
    }
}

// ---------------- conv1x1 (fp32 in, bf16 out) ----------------
__global__ __launch_bounds__(256) void k_conv1x1(const float* __restrict__ in, const float* __restrict__ w,
                                                 const float* __restrict__ bias, unsigned short* __restrict__ out) {
    __shared__ float ts[32*257];
    int blk = blockIdx.x; int b = blk >> 8, h = blk & 255;
    int tid = threadIdx.x;
    const float* src = in + (size_t)b*CH*HW_ + (size_t)h*256;
    for (int idx = tid; idx < 32*256; idx += 256) {
        int c = idx >> 8, ww = idx & 255;
        ts[c*257 + ww] = src[(size_t)c*HW_ + ww];
    }
    __syncthreads();
    float acc[32];
    #pragma unroll
    for (int o = 0; o < 32; ++o) acc[o] = bias[o];
    for (int c = 0; c < 32; ++c) {
        float v = ts[c*257 + tid];
        #pragma unroll
        for (int o = 0; o < 32; ++o) acc[o] += w[o*32 + c] * v;
    }
    unsigned short* dst = out + (size_t)b*CH*HW_ + (size_t)h*256 + tid;
    #pragma unroll
    for (int o = 0; o < 32; ++o) dst[(size_t)o*HW_] = f2bf(acc[o]);
}

// ---------------- Gram via MFMA: Mpart[b][chunk][a][e] = sum_px x[a,px]*dk[px,e] ----------------
__global__ __launch_bounds__(256) void k_gram(const float* __restrict__ x, const unsigned short* __restrict__ dcl,
                                              float* __restrict__ Mpart, float* __restrict__ Sxp, float* __restrict__ Sdp) {
    __shared__ float mred[1024];
    __shared__ float sxred[32];
    __shared__ float sdred[32];
    int blk = blockIdx.x;
    int b = blk >> 7, chunk = blk & 127;
    int tid = threadIdx.x, lane = tid & 63, wv = tid >> 6;
    int l16 = lane & 15, lq = lane >> 4;
    for (int idx = tid; idx < 1024; idx += 256) mred[idx] = 0.0f;
    if (tid < 32) { sxred[tid] = 0.0f; sdred[tid] = 0.0f; }
    __syncthreads();

    const float* xb0 = x + (size_t)b*CH*HW_ + (size_t)l16*HW_;
    const float* xb1 = xb0 + (size_t)16*HW_;
    const unsigned short* db = dcl + (size_t)b*HW_*64;

    f32x4 acc[2][2];
    #pragma unroll
    for (int i = 0; i < 2; ++i)
        #pragma unroll
        for (int j = 0; j < 2; ++j) acc[i][j] = (f32x4)0.0f;
    float sx0 = 0, sx1 = 0, sd0 = 0, sd1 = 0;

    int pxw = chunk*512 + wv*128;
    #pragma unroll
    for (int ks = 0; ks < 4; ++ks) {
        int px = pxw + ks*32 + lq*8;
        float4 xa = *(const float4*)(xb0 + px);
        float4 xc = *(const float4*)(xb0 + px + 4);
        float4 ya = *(const float4*)(xb1 + px);
        float4 yc = *(const float4*)(xb1 + px + 4);
        bf16x8 a0, a1, b0, b1;
        const float* pxa = (const float*)&xa;
        const float* pxc = (const float*)&xc;
        const float* pya = (const float*)&ya;
        const float* pyc = (const float*)&yc;
        #pragma unroll
        for (int j = 0; j < 4; ++j) {
            a0[j]   = (short)f2bf(pxa[j]);  sx0 += pxa[j];
            a0[4+j] = (short)f2bf(pxc[j]);  sx0 += pxc[j];
            a1[j]   = (short)f2bf(pya[j]);  sx1 += pya[j];
            a1[4+j] = (short)f2bf(pyc[j]);  sx1 += pyc[j];
        }
        const unsigned short* dbp = db + (size_t)px*64 + l16;
        #pragma unroll
        for (int j = 0; j < 8; ++j) {
            unsigned short v0 = dbp[j*64];
            unsigned short v1 = dbp[j*64 + 16];
            b0[j] = (short)v0;  sd0 += bf2f(v0);
            b1[j] = (short)v1;  sd1 += bf2f(v1);
        }
        acc[0][0] = __builtin_amdgcn_mfma_f32_16x16x32_bf16(a0, b0, acc[0][0], 0, 0, 0);
        acc[0][1] = __builtin_amdgcn_mfma_f32_16x16x32_bf16(a0, b1, acc[0][1], 0, 0, 0);
        acc[1][0] = __builtin_amdgcn_mfma_f32_16x16x32_bf16(a1, b0, acc[1][0], 0, 0, 0);
        acc[1][1] = __builtin_amdgcn_mfma_f32_16x16x32_bf16(a1, b1, acc[1][1], 0, 0, 0);
    }

    #pragma unroll
    for (int fi = 0; fi < 2; ++fi)
        #pragma unroll
        for (int fj = 0; fj < 2; ++fj)
            #pragma unroll
            for (int r = 0; r < 4; ++r)
                atomicAdd(&mred[(fi*16 + lq*4 + r)*32 + fj*16 + l16], acc[fi][fj][r]);

    sx0 += __shfl_xor(sx0, 16); sx0 += __shfl_xor(sx0, 32);
    sx1 += __shfl_xor(sx1, 16); sx1 += __shfl_xor(sx1, 32);
    sd0 += __shfl_xor(sd0, 16); sd0 += __shfl_xor(sd0, 32);
    sd1 += __shfl_xor(sd1, 16); sd1 += __shfl_xor(sd1, 32);
    if (lane < 16) {
        atomicAdd(&sxred[l16], sx0);
        atomicAdd(&sxred[l16 + 16], sx1);
        atomicAdd(&sdred[l16], sd0);
        atomicAdd(&sdred[l16 + 16], sd1);
    }
    __syncthreads();

    float* mp = Mpart + ((size_t)(b*128 + chunk))*1024;
    for (int idx = tid; idx < 1024; idx += 256) mp[idx] = mred[idx];
    if (tid < 32) {
        Sxp[(b*128 + chunk)*32 + tid] = sxred[tid];
        Sdp[(b*128 + chunk)*32 + tid] = sdred[tid];
    }
}

// ---------------- reduce partials -> M, Sx, Sdk ----------------
__global__ __launch_bounds__(256) void k_reduce(const float* __restrict__ Mpart, const float* __restrict__ Sxp,
                                                const float* __restrict__ Sdp,
                                                float* __restrict__ M, float* __restrict__ Sx, float* __restrict__ Sdk) {
    int b = blockIdx.x >> 2, seg = blockIdx.x & 3;
    int o = seg*256 + threadIdx.x;
    float s = 0;
    for (int c = 0; c < 128; ++c) s += Mpart[((size_t)(b*128 + c))*1024 + o];
    M[b*1024 + o] = s;
    if (seg == 0) {
        if (threadIdx.x < 32) {
            float t = 0;
            for (int c = 0; c < 128; ++c) t += Sxp[(b*128 + c)*32 + threadIdx.x];
            Sx[b*32 + threadIdx.x] = t;
        } else if (threadIdx.x < 64) {
            int e = threadIdx.x - 32;
            float t = 0;
            for (int c = 0; c < 128; ++c) t += Sdp[(b*128 + c)*32 + e];
            Sdk[b*32 + e] = t;
        }
    }
}

// ---------------- tiny attention: one block per batch ----------------
__global__ __launch_bounds__(256) void k_att(const float* __restrict__ M, const float* __restrict__ Sx,
                                              const float* __restrict__ Sdk,
                                              const float* __restrict__ wq, const float* __restrict__ bq,
                                              const float* __restrict__ wk, const float* __restrict__ bk,
                                              const float* __restrict__ wv, const float* __restrict__ bv,
                                              float* __restrict__ att2, float* __restrict__ sout) {
    __shared__ float Mls[1024], T1[1024], attls[32*33];
    __shared__ float wqs[1024], wks[1024], wvs[1024];
    __shared__ float q1[32], k1[32];
    int tid = threadIdx.x;
    int b = blockIdx.x;
    for (int idx = tid; idx < 1024; idx += 256) {
        wqs[idx] = wq[idx]; wks[idx] = wk[idx]; wvs[idx] = wv[idx];
        Mls[idx] = M[b*1024 + idx];
    }
    __syncthreads();
    if (tid < 32) { float s=0; for (int a=0;a<32;++a) s += wqs[tid*32+a]*Sx[b*32+a]; q1[tid]=s; }
    else if (tid < 64) { int d=tid-32; float s=0; for (int e=0;e<32;++e) s += wks[d*32+e]*Sdk[b*32+e]; k1[d]=s; }
    for (int idx = tid; idx < 1024; idx += 256) {
        int c = idx >> 5, e = idx & 31;
        float s = 0;
        for (int a=0;a<32;++a) s += wqs[c*32+a]*Mls[a*32+e];
        T1[idx] = s;
    }
    __syncthreads();
    for (int idx = tid; idx < 1024; idx += 256) {
        int c = idx >> 5, d = idx & 31;
        float s = 0;
        for (int e=0;e<32;++e) s += T1[c*32+e]*wks[d*32+e];
        s += bq[c]*k1[d] + bk[d]*q1[c] + 65536.0f*bq[c]*bk[d];
        attls[c*33+d] = s;
    }
    __syncthreads();
    if (tid < 32) {  // softmax over c for column d=tid
        int d = tid;
        float mx = -1e30f;
        for (int c=0;c<32;++c) mx = fmaxf(mx, attls[c*33+d]);
        float sum = 0;
        for (int c=0;c<32;++c) { float e_ = expf(attls[c*33+d]-mx); attls[c*33+d]=e_; sum+=e_; }
        float inv = 1.0f/sum;
        for (int c=0;c<32;++c) attls[c*33+d] *= inv;
    }
    __syncthreads();
    for (int idx = tid; idx < 1024; idx += 256) {
        int c = idx >> 5, e = idx & 31;
        float s = 0;
        for (int d=0; d<32; ++d) s += attls[c*33+d]*wvs[d*32+e];
        att2[b*1024 + idx] = s;
    }
    if (tid < 32) {
        float s=0; for (int d=0;d<32;++d) s += attls[tid*33+d]*bv[d];
        sout[b*32+tid] = s;
    }
}

// ---------------- inv FFT pass 1: columns, ifftshift gather from planar bf16 G ----------------
__global__ __launch_bounds__(256) void k_fft_inv1(const unsigned short* __restrict__ G, ushort2* __restrict__ Z1T) {
    __shared__ float2 A[16*257];
    __shared__ float2 tw[256];
    build_tw4(tw, 1.0f);
    int blk = blockIdx.x;
    int bc = blk >> 4, w0 = (blk & 15) << 4;
    int b = bc >> 5, c = bc & 31;
    int bs = (b + 2) & 3;
    const float sc = 1.0f/16.0f;
    const unsigned short* gre = G + ((size_t)(bs*CH2 + c + 32))*HW_;
    const unsigned short* gim = G + ((size_t)(bs*CH2 + c))*HW_;
    for (int idx = threadIdx.x; idx < 16*256; idx += 256) {
        int h = idx >> 4, l = idx & 15;
        int hs = (h + 128) & 255;
        int ws = (w0 + l + 128) & 255;
        A[l*257 + h] = make_float2(bf2f(gre[(size_t)hs*256 + ws])*sc, bf2f(gim[(size_t)hs*256 + ws])*sc);
    }
    __syncthreads();
    fft_core4<1>(A, tw);
    ushort2* dst = Z1T + (size_t)bc*HW_;
    for (int idx = threadIdx.x; idx < 16*256; idx += 256) {
        int l = idx >> 8, h = idx & 255;
        float2 v = A[l*257 + h];
        dst[(size_t)(w0 + l)*256 + h] = make_ushort2(f2bf(v.x), f2bf(v.y));
    }
}

// ---------------- inv FFT pass 2: rows, abs -> out ----------------
__global__ __launch_bounds__(256) void k_fft_inv2(const ushort2* __restrict__ Z1T, float* __restrict__ out) {
    __shared__ float2 A[16*257];
    __shared__ float2 tw[256];
    build_tw4(tw, 1.0f);
    int blk = blockIdx.x;
    int bc = blk >> 4, h0 = (blk & 15) << 4;
    const float sc = 1.0f/16.0f;
    const ushort2* src = Z1T + (size_t)bc*HW_ + h0;
    for (int idx = threadIdx.x; idx < 16*256; idx += 256) {
        int w = idx >> 4, l = idx & 15;
        ushort2 v = src[(size_t)w*256 + l];
        A[l*257 + w] = make_float2(bf2f(v.x)*sc, bf2f(v.y)*sc);
    }
    __syncthreads();
    fft_core4<1>(A, tw);
    float* dst = out + (size_t)bc*HW_ + (size_t)h0*256;
    for (int idx = threadIdx.x; idx < 16*256; idx += 256) {
        int l = idx >> 8, w = idx & 255;
        float2 v = A[l*257 + w];
        dst[l*256 + w] = sqrtf(v.x*v.x + v.y*v.y);
    }
}

// ---------------- final: out += att2 @ dv + s  (dv from DFT_cl ct 32..63) ----------------
__global__ __launch_bounds__(256) void k_out(const unsigned short* __restrict__ dcl, const float* __restrict__ att2,
                                             const float* __restrict__ sv, float* __restrict__ out) {
    __shared__ __align__(16) float A2ls[1024];
    __shared__ float svls[32];
    int blk = blockIdx.x; int b = blk >> 8, h = blk & 255;
    int tid = threadIdx.x;
    for (int idx = tid; idx < 1024; idx += 256) A2ls[idx] = att2[b*1024 + idx];
    if (tid < 32) svls[tid] = sv[b*32 + tid];
    __syncthreads();
    int px = tid;
    const uint4* dvp = (const uint4*)(dcl + ((((size_t)b*256 + h)*256 + px)*64 + 32));
    uint4 d0 = dvp[0], d1 = dvp[1];
    unsigned u[8] = {d0.x, d0.y, d0.z, d0.w, d1.x, d1.y, d1.z, d1.w};
    float dv[32];
    #pragma unroll
    for (int i = 0; i < 8; ++i) {
        dv[2*i]   = bf2f(u[i] & 0xffffu);
        dv[2*i+1] = bf2f(u[i] >> 16);
    }
    float accv[32];
    #pragma unroll
    for (int c = 0; c < 32; ++c) accv[c] = svls[c];
    #pragma unroll
    for (int q = 0; q < 8; ++q) {
        #pragma unroll
        for (int c = 0; c < 32; ++c) {
            float4 a4 = *(const float4*)&A2ls[c*32 + q*4];
            accv[c] += a4.x*dv[q*4] + a4.y*dv[q*4+1] + a4.z*dv[q*4+2] + a4.w*dv[q*4+3];
        }
    }
    float* ob = out + (size_t)b*CH*HW_ + (size_t)h*256 + px;
    #pragma unroll
    for (int c = 0; c < 32; ++c) ob[(size_t)c*HW_] += accv[c];
}

extern "C" void kernel_launch(void* const* d_in, const int* in_sizes, int n_in,
                              void* d_out, int out_size, void* d_ws, size_t ws_size,
                              hipStream_t stream) {
    const float* x  = (const float*)d_in[0];
    const float* y  = (const float*)d_in[1];
    const float* wq = (const float*)d_in[2];
    const float* bq = (const float*)d_in[3];
    const float* wk = (const float*)d_in[4];
    const float* bk = (const float*)d_in[5];
    const float* wv = (const float*)d_in[6];
    const float* bv = (const float*)d_in[7];
    const float* wd = (const float*)d_in[8];
    const float* bd = (const float*)d_in[9];
    const float* wc = (const float*)d_in[10];
    const float* bc = (const float*)d_in[11];
    const float* wi = (const float*)d_in[12];
    const float* bi = (const float*)d_in[13];
    float* out = (float*)d_out;

    char* ws = (char*)d_ws;
    size_t o = 0;
    unsigned short* R1   = (unsigned short*)(ws + o); o += (size_t)BATCH*CH*HW_*2;   // 16.7 MB
    ushort2*        CAt  = (ushort2*)(ws + o);        o += (size_t)BATCH*CH*HW_*4;   // 33.5 MB (aliased by Z1T)
    unsigned short* FSHc = (unsigned short*)(ws + o); o += (size_t)BATCH*CH2*HW_*2;  // 33.5 MB
    unsigned short* DFTc = (unsigned short*)(ws + o); o += (size_t)BATCH*CH2*HW_*2;  // 33.5 MB
    unsigned short* Gpl  = (unsigned short*)(ws + o); o += (size_t)BATCH*CH2*HW_*2;  // 33.5 MB
    unsigned short* wpk1 = (unsigned short*)(ws + o); o += 9*64*64*2;
    unsigned short* wpk2 = (unsigned short*)(ws + o); o += 9*64*64*2;
    float*          Mpart= (float*)(ws + o);          o += (size_t)512*1024*4;       // 2 MB
    float*          Sxp  = (float*)(ws + o);          o += 512*32*4;
    float*          Sdp  = (float*)(ws + o);          o += 512*32*4;
    float*          Mb   = (float*)(ws + o);          o += 4096*4;
    float*          Sxb  = (float*)(ws + o);          o += 128*4;
    float*          Sdb  = (float*)(ws + o);          o += 128*4;
    float*          A2b  = (float*)(ws + o);          o += 4096*4;
    float*          Svb  = (float*)(ws + o);          o += 128*4;
    if (ws_size < o) return;

    ushort2* Z1T = CAt;   // alias: CAt dead after fwd2, Z1T written by inv1 later

    k_wpack2<<<288, 256, 0, stream>>>(wc, wi, wpk1, wpk2);
    k_conv1x1<<<1024, 256, 0, stream>>>(y, wd, bd, R1);
    k_fft_fwd1<<<2048, 256, 0, stream>>>(R1, CAt);
    k_fft_fwd2<<<2048, 256, 0, stream>>>(CAt, FSHc);
    k_conv3<0><<<1024, 256, 0, stream>>>(FSHc, wpk1, bc, DFTc);
    k_conv3<1><<<1024, 256, 0, stream>>>(DFTc, wpk2, bi, Gpl);
    k_gram<<<512, 256, 0, stream>>>(x, DFTc, Mpart, Sxp, Sdp);
    k_reduce<<<16, 256, 0, stream>>>(Mpart, Sxp, Sdp, Mb, Sxb, Sdb);
    k_att<<<4, 256, 0, stream>>>(Mb, Sxb, Sdb, wq, bq, wk, bk, wv, bv, A2b, Svb);
    k_fft_inv1<<<2048, 256, 0, stream>>>(Gpl, Z1T);
    k_fft_inv2<<<2048, 256, 0, stream>>>(Z1T, out);
    k_out<<<1024, 256, 0, stream>>>(DFTc, A2b, Svb, out);
}